// Round 16
// baseline (597.953 us; speedup 1.0000x reference)
//
#include <hip/hip_runtime.h>
#include <math.h>

#define NNODES 50000
#define NEDGES 800000
// DIM=64, EDGE_DIM=16, HEADS=4, HC=256

typedef _Float16 f16;
typedef _Float16 f16x2 __attribute__((ext_vector_type(2)));
typedef _Float16 f16x4 __attribute__((ext_vector_type(4)));
typedef _Float16 f16x8 __attribute__((ext_vector_type(8)));
typedef float f32x2 __attribute__((ext_vector_type(2)));
typedef float f32x4 __attribute__((ext_vector_type(4)));
typedef unsigned char uchar;

__device__ inline uint pk16(float a, float b) {
    union { f16x2 h; uint u; } c;
    c.h[0] = (f16)a; c.h[1] = (f16)b;
    return c.u;
}
__device__ inline f16x2 bc16(uint u) {
    union { uint u; f16x2 h; } c; c.u = u; return c.h;
}
__device__ inline float wred_max(float v) {
#pragma unroll
    for (int off = 32; off; off >>= 1) v = fmaxf(v, __shfl_xor(v, off, 64));
    return v;
}
__device__ inline float wred_sum(float v) {
#pragma unroll
    for (int off = 32; off; off >>= 1) v += __shfl_xor(v, off, 64);
    return v;
}
__device__ inline float wred_max16(float v) {
#pragma unroll
    for (int off = 8; off; off >>= 1) v = fmaxf(v, __shfl_xor(v, off, 64));
    return v;
}
__device__ inline float wred_sum16(float v) {
#pragma unroll
    for (int off = 8; off; off >>= 1) v += __shfl_xor(v, off, 64);
    return v;
}
// pack 4 f32 -> 4 fp8 (OCP e4m3) in one uint
__device__ inline uint pk8x4(float a, float b, float c, float d) {
    uint u = 0;
    u = __builtin_amdgcn_cvt_pk_fp8_f32(a, b, u, false);
    u = __builtin_amdgcn_cvt_pk_fp8_f32(c, d, u, true);
    return u;
}

// ---------------- one-time prep kernels ----------------

__global__ __launch_bounds__(256) void k_fold1(
    const float* __restrict__ Wn, const float* __restrict__ We,
    const float* __restrict__ Wa,
    float* __restrict__ wnwa0, float* __restrict__ wnwa2,
    float* __restrict__ wewa1)
{
    int t = threadIdx.x;
    {
        int k = t >> 2, h = t & 3;
        float s0 = 0.f, s2 = 0.f;
        for (int c = 0; c < 64; c++) {
            float wn = Wn[k * 256 + h * 64 + c];
            s0 = fmaf(wn, Wa[h * 192 + c], s0);
            s2 = fmaf(wn, Wa[h * 192 + 128 + c], s2);
        }
        wnwa0[t] = s0;
        wnwa2[t] = s2;
    }
    if (t < 64) {
        int k = t >> 2, h = t & 3;
        float s1 = 0.f;
        for (int c = 0; c < 64; c++)
            s1 = fmaf(We[k * 256 + h * 64 + c], Wa[h * 192 + 64 + c], s1);
        wewa1[t] = s1;
    }
}

__global__ __launch_bounds__(256) void k_fold2(
    const float* __restrict__ Wn, const float* __restrict__ We,
    const float* __restrict__ Wih, const float* __restrict__ Whh,
    const float* __restrict__ Ws, const float* __restrict__ wnwa0,
    const float* __restrict__ wnwa2,
    f16* __restrict__ WeB, f16* __restrict__ WsP, f16* __restrict__ WihP,
    f16* __restrict__ WhhP, f16* __restrict__ WnB, f16* __restrict__ awB)
{
    int gid = blockIdx.x * 256 + threadIdx.x;
    const int STR = 8 * 256;
    for (int idx = gid; idx < 128; idx += STR) {
        int ks = idx >> 6, l = idx & 63;
        int lg = l >> 4, c = l & 15;
        f16* o = awB + (size_t)idx * 8;
        for (int j = 0; j < 8; j++) {
            int k = ks * 32 + lg * 8 + j;
            float v = (c < 4) ? wnwa0[k * 4 + c] : ((c < 8) ? wnwa2[k * 4 + (c - 4)] : 0.f);
            o[j] = (f16)v;
        }
    }
    for (int idx = gid; idx < 2048; idx += STR) {
        int l = idx & 63, tt = (idx >> 6) & 15, ks = idx >> 10;
        int lg = l >> 4, ll = l & 15;
        f16* o = WnB + (size_t)idx * 8;
        for (int j = 0; j < 8; j++)
            o[j] = (f16)Wn[(ks * 32 + lg * 8 + j) * 256 + tt * 16 + ll];
    }
    for (int idx = gid; idx < 1024; idx += STR) {
        int tt = idx >> 6, l = idx & 63;
        int lg = l >> 4, ll = l & 15;
        f16* o = WeB + (size_t)idx * 4;
        for (int j = 0; j < 4; j++)
            o[j] = (f16)We[(lg * 4 + j) * 256 + tt * 16 + ll];
    }
    for (int e = gid; e < 2048; e += STR) {
        int l = e & 63, tt = (e >> 6) & 3, ks = e >> 8;
        int lg = l >> 4, ll = l & 15;
        f16* o = WsP + (size_t)e * 8;
        for (int j = 0; j < 8; j++)
            o[j] = (f16)Ws[(ks * 32 + lg * 8 + j) * 64 + tt * 16 + ll];
    }
    for (int e = gid; e < 1536; e += STR) {
        int l = e & 63, q = e >> 6;
        int tt = q % 12, ks = q / 12;
        int lg = l >> 4, ll = l & 15;
        int outc = tt * 16 + ll;
        for (int j = 0; j < 8; j++) {
            int k = ks * 32 + lg * 8 + j;
            WihP[(size_t)e * 8 + j] = (f16)Wih[outc * 64 + k];
            WhhP[(size_t)e * 8 + j] = (f16)Whh[outc * 64 + k];
        }
    }
}

__global__ __launch_bounds__(256) void k_hist(const int* __restrict__ dst,
                                              int* __restrict__ counts,
                                              int* __restrict__ rankv)
{
    int e = blockIdx.x * 256 + threadIdx.x;
    rankv[e] = atomicAdd(&counts[dst[e]], 1);
}

__global__ __launch_bounds__(1024) void k_scan1(const int* __restrict__ counts,
                                                int* __restrict__ psum)
{
    __shared__ int wsum[16];
    int t = threadIdx.x, wid = t >> 6, lane = t & 63;
    int idx = blockIdx.x * 1024 + t;
    int c = (idx < NNODES) ? counts[idx] : 0;
    int v = c;
#pragma unroll
    for (int off = 32; off; off >>= 1) v += __shfl_xor(v, off, 64);
    if (lane == 0) wsum[wid] = v;
    __syncthreads();
    if (t == 0) {
        int s = 0;
        for (int wk = 0; wk < 16; wk++) s += wsum[wk];
        psum[blockIdx.x] = s;
    }
}

__global__ __launch_bounds__(64) void k_scan0(int* __restrict__ psum, int nb)
{
    if (threadIdx.x == 0) {
        int run = 0;
        for (int b = 0; b < nb; b++) { int s = psum[b]; psum[b] = run; run += s; }
    }
}

__global__ __launch_bounds__(1024) void k_scan2(const int* __restrict__ counts,
                                                const int* __restrict__ psum,
                                                int* __restrict__ row_ptr)
{
    __shared__ int wsum[16];
    int t = threadIdx.x, wid = t >> 6, lane = t & 63;
    int idx = blockIdx.x * 1024 + t;
    int c = (idx < NNODES) ? counts[idx] : 0;
    int v = c;
#pragma unroll
    for (int off = 1; off < 64; off <<= 1) {
        int u = __shfl_up(v, off, 64);
        if (lane >= off) v += u;
    }
    if (lane == 63) wsum[wid] = v;
    __syncthreads();
    int wpre = 0;
#pragma unroll
    for (int wk = 0; wk < 16; wk++) {
        int s = wsum[wk];
        if (wk < wid) wpre += s;
    }
    if (idx < NNODES) row_ptr[idx] = psum[blockIdx.x] + wpre + v - c;
    if (idx == 0) row_ptr[NNODES] = NEDGES;
}

__global__ __launch_bounds__(256) void k_scatter(
    const int* __restrict__ srcv, const int* __restrict__ dstv,
    const int* __restrict__ rankv,
    const float* __restrict__ ea, const float* __restrict__ wewa1,
    const int* __restrict__ row_ptr,
    int* __restrict__ csr_src, uint* __restrict__ ae16c,
    uint* __restrict__ ea16_csr)
{
    __shared__ float w[64];
    int t = threadIdx.x;
    if (t < 64) w[t] = wewa1[t];
    __syncthreads();
    int e = blockIdx.x * 256 + t;
    int d = dstv[e];
    int pos = row_ptr[d] + rankv[e];
    csr_src[pos] = srcv[e];
    const float4* p = (const float4*)(ea + (size_t)e * 16);
    float4 v0 = p[0], v1 = p[1], v2 = p[2], v3 = p[3];
    float eav[16] = {v0.x, v0.y, v0.z, v0.w, v1.x, v1.y, v1.z, v1.w,
                     v2.x, v2.y, v2.z, v2.w, v3.x, v3.y, v3.z, v3.w};
    float a0 = 0.f, a1 = 0.f, a2 = 0.f, a3 = 0.f;
#pragma unroll
    for (int k = 0; k < 16; k++) {
        a0 = fmaf(eav[k], w[k * 4 + 0], a0);
        a1 = fmaf(eav[k], w[k * 4 + 1], a1);
        a2 = fmaf(eav[k], w[k * 4 + 2], a2);
        a3 = fmaf(eav[k], w[k * 4 + 3], a3);
    }
    uint2 ae2; ae2.x = pk16(a0, a1); ae2.y = pk16(a2, a3);
    *(uint2*)(ae16c + (size_t)pos * 2) = ae2;
    uint4 pa, pb;
    pa.x = pk16(eav[0], eav[1]);  pa.y = pk16(eav[2], eav[3]);
    pa.z = pk16(eav[4], eav[5]);  pa.w = pk16(eav[6], eav[7]);
    pb.x = pk16(eav[8], eav[9]);  pb.y = pk16(eav[10], eav[11]);
    pb.z = pk16(eav[12], eav[13]); pb.w = pk16(eav[14], eav[15]);
    uint4* d16 = (uint4*)(ea16_csr + (size_t)pos * 8);
    d16[0] = pa; d16[1] = pb;
}

// ---------------- per-timestep kernels ----------------

// MFMA xp+aij from f32 node features (step 0 only). xp stored FP8 (e4m3):
// xp8[n*256 + ll*16 + tt] -- halves the k_node gather footprint.
__global__ __launch_bounds__(256) void k_xpaij(
    const float* __restrict__ xc, const f16* __restrict__ WnB,
    const f16* __restrict__ awB, uchar* __restrict__ xp8,
    float* __restrict__ aijI, float* __restrict__ aijJ)
{
    int t = threadIdx.x, w = t >> 6, l = t & 63;
    int lg = l >> 4, ll = l & 15;
    int wbase = blockIdx.x * 64 + w * 16;
    int nodeA = wbase + ll;
    int nA = nodeA < NNODES ? nodeA : NNODES - 1;

    f16x8 afr[2];
#pragma unroll
    for (int ks = 0; ks < 2; ks++) {
        const float* xpr = xc + (size_t)nA * 64 + ks * 32 + lg * 8;
        float4 a0 = *(const float4*)xpr;
        float4 a1 = *(const float4*)(xpr + 4);
        f16x8 v;
        v[0] = (f16)a0.x; v[1] = (f16)a0.y; v[2] = (f16)a0.z; v[3] = (f16)a0.w;
        v[4] = (f16)a1.x; v[5] = (f16)a1.y; v[6] = (f16)a1.z; v[7] = (f16)a1.w;
        afr[ks] = v;
    }
    f32x4 zero = {0.f, 0.f, 0.f, 0.f};
    f32x4 c[16];
#pragma unroll
    for (int tt = 0; tt < 16; tt++) c[tt] = zero;
    f32x4 caw = zero;
    const f16x8* WnV = (const f16x8*)WnB;
    const f16x8* awV = (const f16x8*)awB;
#pragma unroll
    for (int ks = 0; ks < 2; ks++) {
        caw = __builtin_amdgcn_mfma_f32_16x16x32_f16(afr[ks], awV[ks * 64 + l], caw, 0, 0, 0);
#pragma unroll
        for (int tt = 0; tt < 16; tt++)
            c[tt] = __builtin_amdgcn_mfma_f32_16x16x32_f16(
                afr[ks], WnV[(ks * 16 + tt) * 64 + l], c[tt], 0, 0, 0);
    }
#pragma unroll
    for (int i = 0; i < 4; i++) {
        int node = wbase + lg * 4 + i;
        if (node < NNODES) {
            uint4 o;
            o.x = pk8x4(c[0][i],  c[1][i],  c[2][i],  c[3][i]);
            o.y = pk8x4(c[4][i],  c[5][i],  c[6][i],  c[7][i]);
            o.z = pk8x4(c[8][i],  c[9][i],  c[10][i], c[11][i]);
            o.w = pk8x4(c[12][i], c[13][i], c[14][i], c[15][i]);
            *(uint4*)(xp8 + (size_t)node * 256 + ll * 16) = o;
            if (ll < 4)      aijI[(size_t)node * 4 + ll] = caw[i];
            else if (ll < 8) aijJ[(size_t)node * 4 + (ll - 4)] = caw[i];
        }
    }
}

#define LEAKY(v) ((v) > 0.f ? (v) : 0.2f * (v))

// Softmax + MFMA aggregation. xp gathers are FP8: 16B/edge-row, decoded with
// v_cvt_pk_f32_fp8 (channel tt lives in byte tt; word h = ttl 0..3 of head h).
__global__ __launch_bounds__(256) void k_node(
    const int* __restrict__ row_ptr, const int* __restrict__ csr_src,
    const uint* __restrict__ ae16c, const float* __restrict__ aijI,
    const float* __restrict__ aijJ, const uchar* __restrict__ xp8,
    const uint* __restrict__ ea16_csr, const f16* __restrict__ WeB,
    f16* __restrict__ aggr16)
{
    __shared__ float wbuf[4][64][4];
    __shared__ uint  eabuf[4][64][8];
    __shared__ int   srcbuf[4][64];
    int t = threadIdx.x, wid = t >> 6, lane = t & 63;
    int ll = lane & 15, g = lane >> 4;
    int n = blockIdx.x * 4 + wid;
    uint4 z4 = {0u, 0u, 0u, 0u};
    *(uint4*)&eabuf[wid][lane][0] = z4;
    *(uint4*)&eabuf[wid][lane][4] = z4;
    f16x4 wb[16];
#pragma unroll
    for (int tt = 0; tt < 16; tt++)
        wb[tt] = *(const f16x4*)(WeB + (size_t)(tt * 64 + lane) * 4);
    int r0 = row_ptr[n], r1 = row_ptr[n + 1];
    int deg = r1 - r0;
    float acc[16];
#pragma unroll
    for (int tt = 0; tt < 16; tt++) acc[tt] = 0.f;
    f32x4 zacc = {0.f, 0.f, 0.f, 0.f};

    auto agg_chunk = [&](int c) {
        int4 s4 = *(const int4*)&srcbuf[wid][c * 16 + g * 4];
        uint4 xA[4];
        xA[0] = *(const uint4*)(xp8 + ((size_t)(uint)s4.x) * 256 + ll * 16);
        xA[1] = *(const uint4*)(xp8 + ((size_t)(uint)s4.y) * 256 + ll * 16);
        xA[2] = *(const uint4*)(xp8 + ((size_t)(uint)s4.z) * 256 + ll * 16);
        xA[3] = *(const uint4*)(xp8 + ((size_t)(uint)s4.w) * 256 + ll * 16);
        f16x4 eaf = *(const f16x4*)((const f16*)&eabuf[wid][c * 16 + ll][0] + g * 4);
        float4 w4 = *(const float4*)&wbuf[wid][c * 16 + ll][0];
        f16 av[4] = {(f16)w4.x, (f16)w4.y, (f16)w4.z, (f16)w4.w};
        f16x4 Ah[4];
#pragma unroll
        for (int h = 0; h < 4; h++)
#pragma unroll
            for (int j = 0; j < 4; j++)
                Ah[h][j] = eaf[j] * av[h];
#pragma unroll
        for (int h = 0; h < 4; h++) {
            f32x4 p0 = __builtin_amdgcn_mfma_f32_16x16x16f16(Ah[h], wb[h * 4 + 0], zacc, 0, 0, 0);
            f32x4 p1 = __builtin_amdgcn_mfma_f32_16x16x16f16(Ah[h], wb[h * 4 + 1], zacc, 0, 0, 0);
            f32x4 p2 = __builtin_amdgcn_mfma_f32_16x16x16f16(Ah[h], wb[h * 4 + 2], zacc, 0, 0, 0);
            f32x4 p3 = __builtin_amdgcn_mfma_f32_16x16x16f16(Ah[h], wb[h * 4 + 3], zacc, 0, 0, 0);
#pragma unroll
            for (int r = 0; r < 4; r++) {
                uint wrd = (h == 0) ? xA[r].x : ((h == 1) ? xA[r].y
                          : ((h == 2) ? xA[r].z : xA[r].w));
                f32x2 lo = __builtin_amdgcn_cvt_pk_f32_fp8(wrd, false);
                f32x2 hi = __builtin_amdgcn_cvt_pk_f32_fp8(wrd, true);
                acc[h * 4 + 0] = fmaf(p0[r], lo[0], acc[h * 4 + 0]);
                acc[h * 4 + 1] = fmaf(p1[r], lo[1], acc[h * 4 + 1]);
                acc[h * 4 + 2] = fmaf(p2[r], hi[0], acc[h * 4 + 2]);
                acc[h * 4 + 3] = fmaf(p3[r], hi[1], acc[h * 4 + 3]);
            }
        }
    };

    if (deg > 0 && deg <= 64) {
        float4 ai = *(const float4*)(aijI + (size_t)n * 4);
        float al0 = -1e30f, al1 = -1e30f, al2 = -1e30f, al3 = -1e30f;
        int sreg = 0;
        if (lane < deg) {
            int p = r0 + lane;
            sreg = csr_src[p];
            uint2 ae2 = *(const uint2*)(ae16c + (size_t)p * 2);
            f16x2 aelo = bc16(ae2.x), aehi = bc16(ae2.y);
            float4 aj = *(const float4*)(aijJ + (size_t)sreg * 4);
            const uint4* ep16 = (const uint4*)(ea16_csr + (size_t)p * 8);
            uint4 ua = ep16[0], ub = ep16[1];
            *(uint4*)&eabuf[wid][lane][0] = ua;
            *(uint4*)&eabuf[wid][lane][4] = ub;
            al0 = LEAKY(ai.x + (float)aelo[0] + aj.x);
            al1 = LEAKY(ai.y + (float)aelo[1] + aj.y);
            al2 = LEAKY(ai.z + (float)aehi[0] + aj.z);
            al3 = LEAKY(ai.w + (float)aehi[1] + aj.w);
        }
        srcbuf[wid][lane] = (lane < deg) ? sreg : 0;
        float m0, m1, m2, m3, s0, s1, s2, s3;
        float p0, p1, p2, p3;
        if (deg <= 16) {
            m0 = wred_max16(al0); m1 = wred_max16(al1);
            m2 = wred_max16(al2); m3 = wred_max16(al3);
            p0 = (lane < deg) ? __expf(al0 - m0) : 0.f;
            p1 = (lane < deg) ? __expf(al1 - m1) : 0.f;
            p2 = (lane < deg) ? __expf(al2 - m2) : 0.f;
            p3 = (lane < deg) ? __expf(al3 - m3) : 0.f;
            s0 = wred_sum16(p0); s1 = wred_sum16(p1);
            s2 = wred_sum16(p2); s3 = wred_sum16(p3);
        } else {
            m0 = wred_max(al0); m1 = wred_max(al1);
            m2 = wred_max(al2); m3 = wred_max(al3);
            p0 = (lane < deg) ? __expf(al0 - m0) : 0.f;
            p1 = (lane < deg) ? __expf(al1 - m1) : 0.f;
            p2 = (lane < deg) ? __expf(al2 - m2) : 0.f;
            p3 = (lane < deg) ? __expf(al3 - m3) : 0.f;
            s0 = wred_sum(p0); s1 = wred_sum(p1);
            s2 = wred_sum(p2); s3 = wred_sum(p3);
        }
        float4 w4v;
        w4v.x = p0 * (1.f / (s0 + 1e-16f));
        w4v.y = p1 * (1.f / (s1 + 1e-16f));
        w4v.z = p2 * (1.f / (s2 + 1e-16f));
        w4v.w = p3 * (1.f / (s3 + 1e-16f));
        *(float4*)&wbuf[wid][lane][0] = w4v;
        asm volatile("s_waitcnt lgkmcnt(0)" ::: "memory");
        int nch = (deg + 15) >> 4;
        for (int c = 0; c < nch; c++) agg_chunk(c);
    } else if (deg > 0) {
        float4 ai = *(const float4*)(aijI + (size_t)n * 4);
        float m0 = -1e30f, m1 = -1e30f, m2 = -1e30f, m3 = -1e30f;
        float s0 = 0.f, s1 = 0.f, s2 = 0.f, s3 = 0.f;
        for (int base = r0; base < r1; base += 64) {
            int p = base + lane;
            if (p < r1) {
                int s = csr_src[p];
                uint2 ae2 = *(const uint2*)(ae16c + (size_t)p * 2);
                f16x2 aelo = bc16(ae2.x), aehi = bc16(ae2.y);
                float4 aj = *(const float4*)(aijJ + (size_t)s * 4);
                float al0 = LEAKY(ai.x + (float)aelo[0] + aj.x);
                float al1 = LEAKY(ai.y + (float)aelo[1] + aj.y);
                float al2 = LEAKY(ai.z + (float)aehi[0] + aj.z);
                float al3 = LEAKY(ai.w + (float)aehi[1] + aj.w);
                float nm;
                nm = fmaxf(m0, al0); s0 = s0 * __expf(m0 - nm) + __expf(al0 - nm); m0 = nm;
                nm = fmaxf(m1, al1); s1 = s1 * __expf(m1 - nm) + __expf(al1 - nm); m1 = nm;
                nm = fmaxf(m2, al2); s2 = s2 * __expf(m2 - nm) + __expf(al2 - nm); m2 = nm;
                nm = fmaxf(m3, al3); s3 = s3 * __expf(m3 - nm) + __expf(al3 - nm); m3 = nm;
            }
        }
#pragma unroll
        for (int off = 32; off; off >>= 1) {
            float om, os, nm;
            om = __shfl_xor(m0, off, 64); os = __shfl_xor(s0, off, 64);
            nm = fmaxf(m0, om); s0 = s0 * __expf(m0 - nm) + os * __expf(om - nm); m0 = nm;
            om = __shfl_xor(m1, off, 64); os = __shfl_xor(s1, off, 64);
            nm = fmaxf(m1, om); s1 = s1 * __expf(m1 - nm) + os * __expf(om - nm); m1 = nm;
            om = __shfl_xor(m2, off, 64); os = __shfl_xor(s2, off, 64);
            nm = fmaxf(m2, om); s2 = s2 * __expf(m2 - nm) + os * __expf(om - nm); m2 = nm;
            om = __shfl_xor(m3, off, 64); os = __shfl_xor(s3, off, 64);
            nm = fmaxf(m3, om); s3 = s3 * __expf(m3 - nm) + os * __expf(om - nm); m3 = nm;
        }
        float rd0 = 1.f / (s0 + 1e-16f), rd1 = 1.f / (s1 + 1e-16f);
        float rd2 = 1.f / (s2 + 1e-16f), rd3 = 1.f / (s3 + 1e-16f);
        for (int base = r0; base < r1; base += 64) {
            int cnt = min(64, r1 - base);
            float4 w4v = {0.f, 0.f, 0.f, 0.f};
            int sreg = 0;
            if (lane < cnt) {
                int p = base + lane;
                sreg = csr_src[p];
                uint2 ae2 = *(const uint2*)(ae16c + (size_t)p * 2);
                f16x2 aelo = bc16(ae2.x), aehi = bc16(ae2.y);
                float4 aj = *(const float4*)(aijJ + (size_t)sreg * 4);
                const uint4* ep16 = (const uint4*)(ea16_csr + (size_t)p * 8);
                uint4 ua = ep16[0], ub = ep16[1];
                *(uint4*)&eabuf[wid][lane][0] = ua;
                *(uint4*)&eabuf[wid][lane][4] = ub;
                float al0 = LEAKY(ai.x + (float)aelo[0] + aj.x);
                float al1 = LEAKY(ai.y + (float)aelo[1] + aj.y);
                float al2 = LEAKY(ai.z + (float)aehi[0] + aj.z);
                float al3 = LEAKY(ai.w + (float)aehi[1] + aj.w);
                w4v.x = __expf(al0 - m0) * rd0;
                w4v.y = __expf(al1 - m1) * rd1;
                w4v.z = __expf(al2 - m2) * rd2;
                w4v.w = __expf(al3 - m3) * rd3;
            } else {
                *(uint4*)&eabuf[wid][lane][0] = z4;
                *(uint4*)&eabuf[wid][lane][4] = z4;
            }
            *(float4*)&wbuf[wid][lane][0] = w4v;
            srcbuf[wid][lane] = (lane < cnt) ? sreg : 0;
            asm volatile("s_waitcnt lgkmcnt(0)" ::: "memory");
            int nch = (cnt + 15) >> 4;
            for (int c = 0; c < nch; c++) agg_chunk(c);
            asm volatile("s_waitcnt lgkmcnt(0)" ::: "memory");
        }
    }
#pragma unroll
    for (int tt = 0; tt < 16; tt++) {
        float v = acc[tt];
        v += __shfl_xor(v, 16, 64);
        v += __shfl_xor(v, 32, 64);
        acc[tt] = v;
    }
    f16* ag = aggr16 + (size_t)n * 256;
#pragma unroll
    for (int tt = 0; tt < 16; tt++)
        if ((tt >> 2) == g) ag[tt * 16 + ll] = (f16)acc[tt];
}

// MFMA k_post: celu(aggr16@WsP+b) -> GRU -> LayerNorm, fused next-step xp/aij.
// xp written FP8. last=1: write final xc to out, skip xp/aij and h_out.
__global__ __launch_bounds__(256) void k_post(
    const f16* __restrict__ aggr16, const f16* __restrict__ WsP,
    const float* __restrict__ bvec, const float* __restrict__ h_in,
    float* __restrict__ h_out, const f16* __restrict__ WihP,
    const f16* __restrict__ WhhP, const float* __restrict__ bih,
    const float* __restrict__ bhh, const float* __restrict__ gamma,
    const float* __restrict__ beta, const f16* __restrict__ WnB,
    const f16* __restrict__ awB, uchar* __restrict__ xp8,
    float* __restrict__ aijI, float* __restrict__ aijJ,
    float* __restrict__ xc_out, int last)
{
    __shared__ __align__(16) f16 m_lds[4][16][72];  // 18 KB, +8 pad
    int t = threadIdx.x, w = t >> 6, l = t & 63;
    int lg = l >> 4, ll = l & 15;
    int nb = blockIdx.x * 64 + w * 16;
    int nodeA = nb + ll;
    int nodeAc = nodeA < NNODES ? nodeA : NNODES - 1;

    f32x4 zero = {0.f, 0.f, 0.f, 0.f};
    f32x4 acc1[4];
#pragma unroll
    for (int tt = 0; tt < 4; tt++) acc1[tt] = zero;
    const f16x8* WsV = (const f16x8*)WsP;
#pragma unroll
    for (int ks = 0; ks < 8; ks++) {
        f16x8 a = *(const f16x8*)(aggr16 + (size_t)nodeAc * 256 + ks * 32 + lg * 8);
#pragma unroll
        for (int tt = 0; tt < 4; tt++) {
            f16x8 b = WsV[(ks * 4 + tt) * 64 + l];
            acc1[tt] = __builtin_amdgcn_mfma_f32_16x16x32_f16(a, b, acc1[tt], 0, 0, 0);
        }
    }
#pragma unroll
    for (int tt = 0; tt < 4; tt++) {
        float bj = bvec[tt * 16 + ll];
#pragma unroll
        for (int i = 0; i < 4; i++) {
            float v = acc1[tt][i] + bj;
            v = v > 0.f ? v : (__expf(v) - 1.f);  // celu
            m_lds[w][lg * 4 + i][tt * 16 + ll] = (f16)v;
        }
    }
    asm volatile("s_waitcnt lgkmcnt(0)" ::: "memory");

    f16x8 mf[2], hf[2];
#pragma unroll
    for (int ks = 0; ks < 2; ks++) {
        mf[ks] = *(const f16x8*)(&m_lds[w][ll][ks * 32 + lg * 8]);
        const float* hp = h_in + (size_t)nodeAc * 64 + ks * 32 + lg * 8;
        float4 h0 = *(const float4*)(hp);
        float4 h1 = *(const float4*)(hp + 4);
        f16x8 hh;
        hh[0] = (f16)h0.x; hh[1] = (f16)h0.y; hh[2] = (f16)h0.z; hh[3] = (f16)h0.w;
        hh[4] = (f16)h1.x; hh[5] = (f16)h1.y; hh[6] = (f16)h1.z; hh[7] = (f16)h1.w;
        hf[ks] = hh;
    }
    f32x4 accI[12], accH[12];
#pragma unroll
    for (int tt = 0; tt < 12; tt++) { accI[tt] = zero; accH[tt] = zero; }
    const f16x8* WiV = (const f16x8*)WihP;
    const f16x8* WhV = (const f16x8*)WhhP;
#pragma unroll
    for (int ks = 0; ks < 2; ks++) {
#pragma unroll
        for (int tt = 0; tt < 12; tt++) {
            f16x8 bi = WiV[(ks * 12 + tt) * 64 + l];
            accI[tt] = __builtin_amdgcn_mfma_f32_16x16x32_f16(mf[ks], bi, accI[tt], 0, 0, 0);
            f16x8 bh = WhV[(ks * 12 + tt) * 64 + l];
            accH[tt] = __builtin_amdgcn_mfma_f32_16x16x32_f16(hf[ks], bh, accH[tt], 0, 0, 0);
        }
    }

    float bI[12], bH[12];
#pragma unroll
    for (int tt = 0; tt < 12; tt++) {
        bI[tt] = bih[ll + 16 * tt];
        bH[tt] = bhh[ll + 16 * tt];
    }
    float ga[4], be[4];
#pragma unroll
    for (int u = 0; u < 4; u++) { ga[u] = gamma[ll + 16 * u]; be[u] = beta[ll + 16 * u]; }
    float hnew[4][4];
#pragma unroll
    for (int i = 0; i < 4; i++) {
        int node = nb + lg * 4 + i;
        int nc = node < NNODES ? node : NNODES - 1;
        const float* hrow = h_in + (size_t)nc * 64 + ll;
#pragma unroll
        for (int u = 0; u < 4; u++) {
            float hv = hrow[16 * u];
            float r = 1.f / (1.f + __expf(-(accI[u][i] + bI[u] + accH[u][i] + bH[u])));
            float z = 1.f / (1.f + __expf(-(accI[u + 4][i] + bI[u + 4] + accH[u + 4][i] + bH[u + 4])));
            float pre = accI[u + 8][i] + bI[u + 8] + r * (accH[u + 8][i] + bH[u + 8]);
            float e2 = __expf(2.f * pre);
            float nn = 1.f - 2.f / (e2 + 1.f);  // tanh, inf-safe
            hnew[i][u] = (1.f - z) * nn + z * hv;
        }
    }
#pragma unroll
    for (int i = 0; i < 4; i++) {
        float s = hnew[i][0] + hnew[i][1] + hnew[i][2] + hnew[i][3];
        float q = hnew[i][0] * hnew[i][0] + hnew[i][1] * hnew[i][1]
                + hnew[i][2] * hnew[i][2] + hnew[i][3] * hnew[i][3];
#pragma unroll
        for (int off = 1; off < 16; off <<= 1) {
            s += __shfl_xor(s, off, 64);
            q += __shfl_xor(q, off, 64);
        }
        float mu = s * (1.f / 64.f);
        float var = q * (1.f / 64.f) - mu * mu;
        float rstd = rsqrtf(var + 1e-5f);
        int node = nb + lg * 4 + i;
        bool ok = node < NNODES;
        float* ho = h_out + (size_t)node * 64 + ll;
        float* xo = xc_out + (size_t)node * 64 + ll;
#pragma unroll
        for (int u = 0; u < 4; u++) {
            float xcv = (hnew[i][u] - mu) * rstd * ga[u] + be[u];
            if (ok) {
                if (last) xo[16 * u] = xcv;
                else      ho[16 * u] = hnew[i][u];
            }
            m_lds[w][lg * 4 + i][16 * u + ll] = (f16)xcv;
        }
    }
    if (last) return;
    asm volatile("s_waitcnt lgkmcnt(0)" ::: "memory");

    // ---- fused next-step xp/aij ----
    f16x8 afr[2];
#pragma unroll
    for (int ks = 0; ks < 2; ks++)
        afr[ks] = *(const f16x8*)(&m_lds[w][ll][ks * 32 + lg * 8]);
    f32x4 c[16];
#pragma unroll
    for (int tt = 0; tt < 16; tt++) c[tt] = zero;
    f32x4 caw = zero;
    const f16x8* WnV = (const f16x8*)WnB;
    const f16x8* awV = (const f16x8*)awB;
#pragma unroll
    for (int ks = 0; ks < 2; ks++) {
        caw = __builtin_amdgcn_mfma_f32_16x16x32_f16(afr[ks], awV[ks * 64 + l], caw, 0, 0, 0);
#pragma unroll
        for (int tt = 0; tt < 16; tt++)
            c[tt] = __builtin_amdgcn_mfma_f32_16x16x32_f16(
                afr[ks], WnV[(ks * 16 + tt) * 64 + l], c[tt], 0, 0, 0);
    }
#pragma unroll
    for (int i = 0; i < 4; i++) {
        int node = nb + lg * 4 + i;
        if (node < NNODES) {
            uint4 o;
            o.x = pk8x4(c[0][i],  c[1][i],  c[2][i],  c[3][i]);
            o.y = pk8x4(c[4][i],  c[5][i],  c[6][i],  c[7][i]);
            o.z = pk8x4(c[8][i],  c[9][i],  c[10][i], c[11][i]);
            o.w = pk8x4(c[12][i], c[13][i], c[14][i], c[15][i]);
            *(uint4*)(xp8 + (size_t)node * 256 + ll * 16) = o;
            if (ll < 4)      aijI[(size_t)node * 4 + ll] = caw[i];
            else if (ll < 8) aijJ[(size_t)node * 4 + (ll - 4)] = caw[i];
        }
    }
}

// ---------------- launcher ----------------

extern "C" void kernel_launch(void* const* d_in, const int* in_sizes, int n_in,
                              void* d_out, int out_size, void* d_ws, size_t ws_size,
                              hipStream_t stream)
{
    const float* x         = (const float*)d_in[0];
    const int*   edge_index= (const int*)d_in[1];
    const float* edge_attr = (const float*)d_in[2];
    const float* Wn        = (const float*)d_in[3];
    const float* We        = (const float*)d_in[4];
    const float* Wa        = (const float*)d_in[5];
    const float* Ws        = (const float*)d_in[6];
    const float* bv        = (const float*)d_in[7];
    const float* Wih       = (const float*)d_in[8];
    const float* Whh       = (const float*)d_in[9];
    const float* bih       = (const float*)d_in[10];
    const float* bhh       = (const float*)d_in[11];
    const float* gamma     = (const float*)d_in[12];
    const float* beta      = (const float*)d_in[13];
    float* out = (float*)d_out;

    const int* src = edge_index;
    const int* dst = edge_index + NEDGES;

    char* w = (char*)d_ws;
    auto alloc = [&](size_t bytes) {
        char* p = w;
        w += (bytes + 255) & ~(size_t)255;
        return p;
    };
    uchar* xp8      = (uchar*)alloc((size_t)NNODES * 256);
    f16*   aggr16   = (f16*)alloc((size_t)NNODES * 256 * 2);
    uint*  ae16c    = (uint*)alloc((size_t)NEDGES * 2 * 4);
    uint*  ea16_csr = (uint*)alloc((size_t)NEDGES * 8 * 4);
    float* hbuf     = (float*)alloc((size_t)NNODES * 64 * 4);
    float* aijI     = (float*)alloc((size_t)NNODES * 4 * 4);
    float* aijJ     = (float*)alloc((size_t)NNODES * 4 * 4);
    int*   counts   = (int*)alloc((size_t)NNODES * 4);
    int*   rankv    = (int*)alloc((size_t)NEDGES * 4);
    int*   row_ptr  = (int*)alloc((size_t)(NNODES + 1) * 4);
    int*   csr_src  = (int*)alloc((size_t)NEDGES * 4);
    int*   psum     = (int*)alloc(64 * 4);
    float* wnwa0    = (float*)alloc(256 * 4);
    float* wnwa2    = (float*)alloc(256 * 4);
    float* wewa1    = (float*)alloc(64 * 4);
    f16*   WeB      = (f16*)alloc(1024 * 4 * 2);
    f16*   WsP      = (f16*)alloc(2048 * 8 * 2);
    f16*   WihP     = (f16*)alloc(1536 * 8 * 2);
    f16*   WhhP     = (f16*)alloc(1536 * 8 * 2);
    f16*   WnB      = (f16*)alloc(2048 * 8 * 2);
    f16*   awB      = (f16*)alloc(128 * 8 * 2);

    const int NSCAN = (NNODES + 1023) / 1024;   // 49

    k_fold1<<<1, 256, 0, stream>>>(Wn, We, Wa, wnwa0, wnwa2, wewa1);
    hipMemsetAsync(counts, 0, (size_t)NNODES * 4, stream);
    k_hist<<<NEDGES / 256, 256, 0, stream>>>(dst, counts, rankv);
    k_fold2<<<8, 256, 0, stream>>>(Wn, We, Wih, Whh, Ws, wnwa0, wnwa2,
                                   WeB, WsP, WihP, WhhP, WnB, awB);
    k_scan1<<<NSCAN, 1024, 0, stream>>>(counts, psum);
    k_scan0<<<1, 64, 0, stream>>>(psum, NSCAN);
    k_scan2<<<NSCAN, 1024, 0, stream>>>(counts, psum, row_ptr);
    k_scatter<<<NEDGES / 256, 256, 0, stream>>>(src, dst, rankv, edge_attr,
                                                wewa1, row_ptr, csr_src,
                                                ae16c, ea16_csr);

    k_xpaij<<<(NNODES + 63) / 64, 256, 0, stream>>>(x, WnB, awB,
                                                    xp8, aijI, aijJ);
    for (int step = 0; step < 3; step++) {
        const float* h_in = (step == 0) ? x : hbuf;
        k_node<<<NNODES / 4, 256, 0, stream>>>(row_ptr, csr_src, ae16c, aijI,
                                               aijJ, xp8, ea16_csr, WeB, aggr16);
        k_post<<<(NNODES + 63) / 64, 256, 0, stream>>>(
            aggr16, WsP, bv, h_in, hbuf, WihP, WhhP, bih, bhh, gamma, beta,
            WnB, awB, xp8, aijI, aijJ, out, step == 2 ? 1 : 0);
    }
}

// Round 17
// 511.315 us; speedup vs baseline: 1.1694x; 1.1694x over previous
//
#include <hip/hip_runtime.h>
#include <math.h>

#define NNODES 50000
#define NEDGES 800000
// DIM=64, EDGE_DIM=16, HEADS=4, HC=256

typedef _Float16 f16;
typedef _Float16 f16x2 __attribute__((ext_vector_type(2)));
typedef _Float16 f16x4 __attribute__((ext_vector_type(4)));
typedef _Float16 f16x8 __attribute__((ext_vector_type(8)));
typedef float f32x4 __attribute__((ext_vector_type(4)));

// guaranteed single-instruction f32 += f32 * f16(half of WRD)
#define FMAMIX_LO(ACC, PV, WRD) \
    asm("v_fma_mix_f32 %0, %1, %2, %0 op_sel_hi:[0,1,0]" \
        : "+v"(ACC) : "v"(PV), "v"(WRD))
#define FMAMIX_HI(ACC, PV, WRD) \
    asm("v_fma_mix_f32 %0, %1, %2, %0 op_sel:[0,1,0] op_sel_hi:[0,1,0]" \
        : "+v"(ACC) : "v"(PV), "v"(WRD))

__device__ inline uint pk16(float a, float b) {
    union { f16x2 h; uint u; } c;
    c.h[0] = (f16)a; c.h[1] = (f16)b;
    return c.u;
}
__device__ inline f16x2 bc16(uint u) {
    union { uint u; f16x2 h; } c; c.u = u; return c.h;
}
__device__ inline float wred_max(float v) {
#pragma unroll
    for (int off = 32; off; off >>= 1) v = fmaxf(v, __shfl_xor(v, off, 64));
    return v;
}
__device__ inline float wred_sum(float v) {
#pragma unroll
    for (int off = 32; off; off >>= 1) v += __shfl_xor(v, off, 64);
    return v;
}
__device__ inline float wred_max16(float v) {
#pragma unroll
    for (int off = 8; off; off >>= 1) v = fmaxf(v, __shfl_xor(v, off, 64));
    return v;
}
__device__ inline float wred_sum16(float v) {
#pragma unroll
    for (int off = 8; off; off >>= 1) v += __shfl_xor(v, off, 64);
    return v;
}

// ---------------- one-time prep kernels ----------------

__global__ __launch_bounds__(256) void k_fold1(
    const float* __restrict__ Wn, const float* __restrict__ We,
    const float* __restrict__ Wa,
    float* __restrict__ wnwa0, float* __restrict__ wnwa2,
    float* __restrict__ wewa1)
{
    int t = threadIdx.x;
    {
        int k = t >> 2, h = t & 3;
        float s0 = 0.f, s2 = 0.f;
        for (int c = 0; c < 64; c++) {
            float wn = Wn[k * 256 + h * 64 + c];
            s0 = fmaf(wn, Wa[h * 192 + c], s0);
            s2 = fmaf(wn, Wa[h * 192 + 128 + c], s2);
        }
        wnwa0[t] = s0;
        wnwa2[t] = s2;
    }
    if (t < 64) {
        int k = t >> 2, h = t & 3;
        float s1 = 0.f;
        for (int c = 0; c < 64; c++)
            s1 = fmaf(We[k * 256 + h * 64 + c], Wa[h * 192 + 64 + c], s1);
        wewa1[t] = s1;
    }
}

__global__ __launch_bounds__(256) void k_fold2(
    const float* __restrict__ Wn, const float* __restrict__ We,
    const float* __restrict__ Wih, const float* __restrict__ Whh,
    const float* __restrict__ Ws, const float* __restrict__ wnwa0,
    const float* __restrict__ wnwa2,
    f16* __restrict__ WeB, f16* __restrict__ WsP, f16* __restrict__ WihP,
    f16* __restrict__ WhhP, f16* __restrict__ WnB, f16* __restrict__ awB)
{
    int gid = blockIdx.x * 256 + threadIdx.x;
    const int STR = 8 * 256;
    for (int idx = gid; idx < 128; idx += STR) {
        int ks = idx >> 6, l = idx & 63;
        int lg = l >> 4, c = l & 15;
        f16* o = awB + (size_t)idx * 8;
        for (int j = 0; j < 8; j++) {
            int k = ks * 32 + lg * 8 + j;
            float v = (c < 4) ? wnwa0[k * 4 + c] : ((c < 8) ? wnwa2[k * 4 + (c - 4)] : 0.f);
            o[j] = (f16)v;
        }
    }
    for (int idx = gid; idx < 2048; idx += STR) {
        int l = idx & 63, tt = (idx >> 6) & 15, ks = idx >> 10;
        int lg = l >> 4, ll = l & 15;
        f16* o = WnB + (size_t)idx * 8;
        for (int j = 0; j < 8; j++)
            o[j] = (f16)Wn[(ks * 32 + lg * 8 + j) * 256 + tt * 16 + ll];
    }
    for (int idx = gid; idx < 1024; idx += STR) {
        int tt = idx >> 6, l = idx & 63;
        int lg = l >> 4, ll = l & 15;
        f16* o = WeB + (size_t)idx * 4;
        for (int j = 0; j < 4; j++)
            o[j] = (f16)We[(lg * 4 + j) * 256 + tt * 16 + ll];
    }
    for (int e = gid; e < 2048; e += STR) {
        int l = e & 63, tt = (e >> 6) & 3, ks = e >> 8;
        int lg = l >> 4, ll = l & 15;
        f16* o = WsP + (size_t)e * 8;
        for (int j = 0; j < 8; j++)
            o[j] = (f16)Ws[(ks * 32 + lg * 8 + j) * 64 + tt * 16 + ll];
    }
    for (int e = gid; e < 1536; e += STR) {
        int l = e & 63, q = e >> 6;
        int tt = q % 12, ks = q / 12;
        int lg = l >> 4, ll = l & 15;
        int outc = tt * 16 + ll;
        for (int j = 0; j < 8; j++) {
            int k = ks * 32 + lg * 8 + j;
            WihP[(size_t)e * 8 + j] = (f16)Wih[outc * 64 + k];
            WhhP[(size_t)e * 8 + j] = (f16)Whh[outc * 64 + k];
        }
    }
}

__global__ __launch_bounds__(256) void k_hist(const int* __restrict__ dst,
                                              int* __restrict__ counts,
                                              int* __restrict__ rankv)
{
    int e = blockIdx.x * 256 + threadIdx.x;
    rankv[e] = atomicAdd(&counts[dst[e]], 1);
}

__global__ __launch_bounds__(1024) void k_scan1(const int* __restrict__ counts,
                                                int* __restrict__ psum)
{
    __shared__ int wsum[16];
    int t = threadIdx.x, wid = t >> 6, lane = t & 63;
    int idx = blockIdx.x * 1024 + t;
    int c = (idx < NNODES) ? counts[idx] : 0;
    int v = c;
#pragma unroll
    for (int off = 32; off; off >>= 1) v += __shfl_xor(v, off, 64);
    if (lane == 0) wsum[wid] = v;
    __syncthreads();
    if (t == 0) {
        int s = 0;
        for (int wk = 0; wk < 16; wk++) s += wsum[wk];
        psum[blockIdx.x] = s;
    }
}

__global__ __launch_bounds__(64) void k_scan0(int* __restrict__ psum, int nb)
{
    if (threadIdx.x == 0) {
        int run = 0;
        for (int b = 0; b < nb; b++) { int s = psum[b]; psum[b] = run; run += s; }
    }
}

__global__ __launch_bounds__(1024) void k_scan2(const int* __restrict__ counts,
                                                const int* __restrict__ psum,
                                                int* __restrict__ row_ptr)
{
    __shared__ int wsum[16];
    int t = threadIdx.x, wid = t >> 6, lane = t & 63;
    int idx = blockIdx.x * 1024 + t;
    int c = (idx < NNODES) ? counts[idx] : 0;
    int v = c;
#pragma unroll
    for (int off = 1; off < 64; off <<= 1) {
        int u = __shfl_up(v, off, 64);
        if (lane >= off) v += u;
    }
    if (lane == 63) wsum[wid] = v;
    __syncthreads();
    int wpre = 0;
#pragma unroll
    for (int wk = 0; wk < 16; wk++) {
        int s = wsum[wk];
        if (wk < wid) wpre += s;
    }
    if (idx < NNODES) row_ptr[idx] = psum[blockIdx.x] + wpre + v - c;
    if (idx == 0) row_ptr[NNODES] = NEDGES;
}

__global__ __launch_bounds__(256) void k_scatter(
    const int* __restrict__ srcv, const int* __restrict__ dstv,
    const int* __restrict__ rankv,
    const float* __restrict__ ea, const float* __restrict__ wewa1,
    const int* __restrict__ row_ptr,
    int* __restrict__ csr_src, uint* __restrict__ ae16c,
    uint* __restrict__ ea16_csr)
{
    __shared__ float w[64];
    int t = threadIdx.x;
    if (t < 64) w[t] = wewa1[t];
    __syncthreads();
    int e = blockIdx.x * 256 + t;
    int d = dstv[e];
    int pos = row_ptr[d] + rankv[e];
    csr_src[pos] = srcv[e];
    const float4* p = (const float4*)(ea + (size_t)e * 16);
    float4 v0 = p[0], v1 = p[1], v2 = p[2], v3 = p[3];
    float eav[16] = {v0.x, v0.y, v0.z, v0.w, v1.x, v1.y, v1.z, v1.w,
                     v2.x, v2.y, v2.z, v2.w, v3.x, v3.y, v3.z, v3.w};
    float a0 = 0.f, a1 = 0.f, a2 = 0.f, a3 = 0.f;
#pragma unroll
    for (int k = 0; k < 16; k++) {
        a0 = fmaf(eav[k], w[k * 4 + 0], a0);
        a1 = fmaf(eav[k], w[k * 4 + 1], a1);
        a2 = fmaf(eav[k], w[k * 4 + 2], a2);
        a3 = fmaf(eav[k], w[k * 4 + 3], a3);
    }
    uint2 ae2; ae2.x = pk16(a0, a1); ae2.y = pk16(a2, a3);
    *(uint2*)(ae16c + (size_t)pos * 2) = ae2;
    uint4 pa, pb;
    pa.x = pk16(eav[0], eav[1]);  pa.y = pk16(eav[2], eav[3]);
    pa.z = pk16(eav[4], eav[5]);  pa.w = pk16(eav[6], eav[7]);
    pb.x = pk16(eav[8], eav[9]);  pb.y = pk16(eav[10], eav[11]);
    pb.z = pk16(eav[12], eav[13]); pb.w = pk16(eav[14], eav[15]);
    uint4* d16 = (uint4*)(ea16_csr + (size_t)pos * 8);
    d16[0] = pa; d16[1] = pb;
}

// ---------------- per-timestep kernels ----------------

// MFMA xp+aij from f32 node features (step 0 only), f16 xp.
__global__ __launch_bounds__(256) void k_xpaij(
    const float* __restrict__ xc, const f16* __restrict__ WnB,
    const f16* __restrict__ awB, f16* __restrict__ xp16,
    float* __restrict__ aijI, float* __restrict__ aijJ)
{
    int t = threadIdx.x, w = t >> 6, l = t & 63;
    int lg = l >> 4, ll = l & 15;
    int wbase = blockIdx.x * 64 + w * 16;
    int nodeA = wbase + ll;
    int nA = nodeA < NNODES ? nodeA : NNODES - 1;

    f16x8 afr[2];
#pragma unroll
    for (int ks = 0; ks < 2; ks++) {
        const float* xpr = xc + (size_t)nA * 64 + ks * 32 + lg * 8;
        float4 a0 = *(const float4*)xpr;
        float4 a1 = *(const float4*)(xpr + 4);
        f16x8 v;
        v[0] = (f16)a0.x; v[1] = (f16)a0.y; v[2] = (f16)a0.z; v[3] = (f16)a0.w;
        v[4] = (f16)a1.x; v[5] = (f16)a1.y; v[6] = (f16)a1.z; v[7] = (f16)a1.w;
        afr[ks] = v;
    }
    f32x4 zero = {0.f, 0.f, 0.f, 0.f};
    f32x4 c[16];
#pragma unroll
    for (int tt = 0; tt < 16; tt++) c[tt] = zero;
    f32x4 caw = zero;
    const f16x8* WnV = (const f16x8*)WnB;
    const f16x8* awV = (const f16x8*)awB;
#pragma unroll
    for (int ks = 0; ks < 2; ks++) {
        caw = __builtin_amdgcn_mfma_f32_16x16x32_f16(afr[ks], awV[ks * 64 + l], caw, 0, 0, 0);
#pragma unroll
        for (int tt = 0; tt < 16; tt++)
            c[tt] = __builtin_amdgcn_mfma_f32_16x16x32_f16(
                afr[ks], WnV[(ks * 16 + tt) * 64 + l], c[tt], 0, 0, 0);
    }
#pragma unroll
    for (int i = 0; i < 4; i++) {
        int node = wbase + lg * 4 + i;
        if (node < NNODES) {
            f16x8 o0, o1;
#pragma unroll
            for (int tt = 0; tt < 8; tt++) o0[tt] = (f16)c[tt][i];
#pragma unroll
            for (int tt = 0; tt < 8; tt++) o1[tt] = (f16)c[8 + tt][i];
            f16* dstp = xp16 + (size_t)node * 256 + ll * 16;
            *(f16x8*)dstp = o0;
            *(f16x8*)(dstp + 8) = o1;
            if (ll < 4)      aijI[(size_t)node * 4 + ll] = caw[i];
            else if (ll < 8) aijJ[(size_t)node * 4 + (ll - 4)] = caw[i];
        }
    }
}

#define LEAKY(v) ((v) > 0.f ? (v) : 0.2f * (v))

// Softmax + MFMA aggregation. agg_chunk splits the 32B gather into two 16B
// halves (xA for heads 0-1, xB for heads 2-3) to cut peak live gather regs
// 32 -> ~16-24: k_node is occupancy-bound and VGPR is the binding resource
// (R16 lesson: fp8 halved FETCH but VGPR 72->92 cost 25% perf).
__global__ __launch_bounds__(256) void k_node(
    const int* __restrict__ row_ptr, const int* __restrict__ csr_src,
    const uint* __restrict__ ae16c, const float* __restrict__ aijI,
    const float* __restrict__ aijJ, const f16* __restrict__ xp16,
    const uint* __restrict__ ea16_csr, const f16* __restrict__ WeB,
    f16* __restrict__ aggr16)
{
    __shared__ float wbuf[4][64][4];
    __shared__ uint  eabuf[4][64][8];
    __shared__ int   srcbuf[4][64];
    int t = threadIdx.x, wid = t >> 6, lane = t & 63;
    int ll = lane & 15, g = lane >> 4;
    int n = blockIdx.x * 4 + wid;
    uint4 z4 = {0u, 0u, 0u, 0u};
    *(uint4*)&eabuf[wid][lane][0] = z4;
    *(uint4*)&eabuf[wid][lane][4] = z4;
    f16x4 wb[16];
#pragma unroll
    for (int tt = 0; tt < 16; tt++)
        wb[tt] = *(const f16x4*)(WeB + (size_t)(tt * 64 + lane) * 4);
    int r0 = row_ptr[n], r1 = row_ptr[n + 1];
    int deg = r1 - r0;
    float acc[16];
#pragma unroll
    for (int tt = 0; tt < 16; tt++) acc[tt] = 0.f;
    f32x4 zacc = {0.f, 0.f, 0.f, 0.f};

    auto agg_chunk = [&](int c) {
        int4 s4 = *(const int4*)&srcbuf[wid][c * 16 + g * 4];
        const f16* xr0 = xp16 + ((size_t)(uint)s4.x) * 256 + ll * 16;
        const f16* xr1 = xp16 + ((size_t)(uint)s4.y) * 256 + ll * 16;
        const f16* xr2 = xp16 + ((size_t)(uint)s4.z) * 256 + ll * 16;
        const f16* xr3 = xp16 + ((size_t)(uint)s4.w) * 256 + ll * 16;
        f16x4 eaf = *(const f16x4*)((const f16*)&eabuf[wid][c * 16 + ll][0] + g * 4);
        float4 w4 = *(const float4*)&wbuf[wid][c * 16 + ll][0];
        f16 av[4] = {(f16)w4.x, (f16)w4.y, (f16)w4.z, (f16)w4.w};
        f16x4 Ah[4];
#pragma unroll
        for (int h = 0; h < 4; h++)
#pragma unroll
            for (int j = 0; j < 4; j++)
                Ah[h][j] = eaf[j] * av[h];
        // ---- first half: heads 0-1, gather bytes 0..15 ----
        {
            uint4 xA[4];
            xA[0] = *(const uint4*)xr0;
            xA[1] = *(const uint4*)xr1;
            xA[2] = *(const uint4*)xr2;
            xA[3] = *(const uint4*)xr3;
#pragma unroll
            for (int h = 0; h < 2; h++) {
                f32x4 p0 = __builtin_amdgcn_mfma_f32_16x16x16f16(Ah[h], wb[h * 4 + 0], zacc, 0, 0, 0);
                f32x4 p1 = __builtin_amdgcn_mfma_f32_16x16x16f16(Ah[h], wb[h * 4 + 1], zacc, 0, 0, 0);
                f32x4 p2 = __builtin_amdgcn_mfma_f32_16x16x16f16(Ah[h], wb[h * 4 + 2], zacc, 0, 0, 0);
                f32x4 p3 = __builtin_amdgcn_mfma_f32_16x16x16f16(Ah[h], wb[h * 4 + 3], zacc, 0, 0, 0);
#pragma unroll
                for (int ttl = 0; ttl < 4; ttl++) {
                    int tt = h * 4 + ttl;
                    f32x4 pv = ttl == 0 ? p0 : (ttl == 1 ? p1 : (ttl == 2 ? p2 : p3));
                    int q = tt & 7;
#pragma unroll
                    for (int r = 0; r < 4; r++) {
                        uint wrd = (q >> 1) == 0 ? xA[r].x
                                 : ((q >> 1) == 1 ? xA[r].y : ((q >> 1) == 2 ? xA[r].z : xA[r].w));
                        float pvf = pv[r];
                        if (q & 1) FMAMIX_HI(acc[tt], pvf, wrd);
                        else       FMAMIX_LO(acc[tt], pvf, wrd);
                    }
                }
            }
        }
        // ---- second half: heads 2-3, gather bytes 16..31 ----
        {
            uint4 xB[4];
            xB[0] = *(const uint4*)(xr0 + 8);
            xB[1] = *(const uint4*)(xr1 + 8);
            xB[2] = *(const uint4*)(xr2 + 8);
            xB[3] = *(const uint4*)(xr3 + 8);
#pragma unroll
            for (int h = 2; h < 4; h++) {
                f32x4 p0 = __builtin_amdgcn_mfma_f32_16x16x16f16(Ah[h], wb[h * 4 + 0], zacc, 0, 0, 0);
                f32x4 p1 = __builtin_amdgcn_mfma_f32_16x16x16f16(Ah[h], wb[h * 4 + 1], zacc, 0, 0, 0);
                f32x4 p2 = __builtin_amdgcn_mfma_f32_16x16x16f16(Ah[h], wb[h * 4 + 2], zacc, 0, 0, 0);
                f32x4 p3 = __builtin_amdgcn_mfma_f32_16x16x16f16(Ah[h], wb[h * 4 + 3], zacc, 0, 0, 0);
#pragma unroll
                for (int ttl = 0; ttl < 4; ttl++) {
                    int tt = h * 4 + ttl;
                    f32x4 pv = ttl == 0 ? p0 : (ttl == 1 ? p1 : (ttl == 2 ? p2 : p3));
                    int q = tt & 7;
#pragma unroll
                    for (int r = 0; r < 4; r++) {
                        uint wrd = (q >> 1) == 0 ? xB[r].x
                                 : ((q >> 1) == 1 ? xB[r].y : ((q >> 1) == 2 ? xB[r].z : xB[r].w));
                        float pvf = pv[r];
                        if (q & 1) FMAMIX_HI(acc[tt], pvf, wrd);
                        else       FMAMIX_LO(acc[tt], pvf, wrd);
                    }
                }
            }
        }
    };

    if (deg > 0 && deg <= 64) {
        float4 ai = *(const float4*)(aijI + (size_t)n * 4);
        float al0 = -1e30f, al1 = -1e30f, al2 = -1e30f, al3 = -1e30f;
        int sreg = 0;
        if (lane < deg) {
            int p = r0 + lane;
            sreg = csr_src[p];
            uint2 ae2 = *(const uint2*)(ae16c + (size_t)p * 2);
            f16x2 aelo = bc16(ae2.x), aehi = bc16(ae2.y);
            float4 aj = *(const float4*)(aijJ + (size_t)sreg * 4);
            const uint4* ep16 = (const uint4*)(ea16_csr + (size_t)p * 8);
            uint4 ua = ep16[0], ub = ep16[1];
            *(uint4*)&eabuf[wid][lane][0] = ua;
            *(uint4*)&eabuf[wid][lane][4] = ub;
            al0 = LEAKY(ai.x + (float)aelo[0] + aj.x);
            al1 = LEAKY(ai.y + (float)aelo[1] + aj.y);
            al2 = LEAKY(ai.z + (float)aehi[0] + aj.z);
            al3 = LEAKY(ai.w + (float)aehi[1] + aj.w);
        }
        srcbuf[wid][lane] = (lane < deg) ? sreg : 0;
        float m0, m1, m2, m3, s0, s1, s2, s3;
        float p0, p1, p2, p3;
        if (deg <= 16) {
            m0 = wred_max16(al0); m1 = wred_max16(al1);
            m2 = wred_max16(al2); m3 = wred_max16(al3);
            p0 = (lane < deg) ? __expf(al0 - m0) : 0.f;
            p1 = (lane < deg) ? __expf(al1 - m1) : 0.f;
            p2 = (lane < deg) ? __expf(al2 - m2) : 0.f;
            p3 = (lane < deg) ? __expf(al3 - m3) : 0.f;
            s0 = wred_sum16(p0); s1 = wred_sum16(p1);
            s2 = wred_sum16(p2); s3 = wred_sum16(p3);
        } else {
            m0 = wred_max(al0); m1 = wred_max(al1);
            m2 = wred_max(al2); m3 = wred_max(al3);
            p0 = (lane < deg) ? __expf(al0 - m0) : 0.f;
            p1 = (lane < deg) ? __expf(al1 - m1) : 0.f;
            p2 = (lane < deg) ? __expf(al2 - m2) : 0.f;
            p3 = (lane < deg) ? __expf(al3 - m3) : 0.f;
            s0 = wred_sum(p0); s1 = wred_sum(p1);
            s2 = wred_sum(p2); s3 = wred_sum(p3);
        }
        float4 w4v;
        w4v.x = p0 * (1.f / (s0 + 1e-16f));
        w4v.y = p1 * (1.f / (s1 + 1e-16f));
        w4v.z = p2 * (1.f / (s2 + 1e-16f));
        w4v.w = p3 * (1.f / (s3 + 1e-16f));
        *(float4*)&wbuf[wid][lane][0] = w4v;
        asm volatile("s_waitcnt lgkmcnt(0)" ::: "memory");
        int nch = (deg + 15) >> 4;
        for (int c = 0; c < nch; c++) agg_chunk(c);
    } else if (deg > 0) {
        float4 ai = *(const float4*)(aijI + (size_t)n * 4);
        float m0 = -1e30f, m1 = -1e30f, m2 = -1e30f, m3 = -1e30f;
        float s0 = 0.f, s1 = 0.f, s2 = 0.f, s3 = 0.f;
        for (int base = r0; base < r1; base += 64) {
            int p = base + lane;
            if (p < r1) {
                int s = csr_src[p];
                uint2 ae2 = *(const uint2*)(ae16c + (size_t)p * 2);
                f16x2 aelo = bc16(ae2.x), aehi = bc16(ae2.y);
                float4 aj = *(const float4*)(aijJ + (size_t)s * 4);
                float al0 = LEAKY(ai.x + (float)aelo[0] + aj.x);
                float al1 = LEAKY(ai.y + (float)aelo[1] + aj.y);
                float al2 = LEAKY(ai.z + (float)aehi[0] + aj.z);
                float al3 = LEAKY(ai.w + (float)aehi[1] + aj.w);
                float nm;
                nm = fmaxf(m0, al0); s0 = s0 * __expf(m0 - nm) + __expf(al0 - nm); m0 = nm;
                nm = fmaxf(m1, al1); s1 = s1 * __expf(m1 - nm) + __expf(al1 - nm); m1 = nm;
                nm = fmaxf(m2, al2); s2 = s2 * __expf(m2 - nm) + __expf(al2 - nm); m2 = nm;
                nm = fmaxf(m3, al3); s3 = s3 * __expf(m3 - nm) + __expf(al3 - nm); m3 = nm;
            }
        }
#pragma unroll
        for (int off = 32; off; off >>= 1) {
            float om, os, nm;
            om = __shfl_xor(m0, off, 64); os = __shfl_xor(s0, off, 64);
            nm = fmaxf(m0, om); s0 = s0 * __expf(m0 - nm) + os * __expf(om - nm); m0 = nm;
            om = __shfl_xor(m1, off, 64); os = __shfl_xor(s1, off, 64);
            nm = fmaxf(m1, om); s1 = s1 * __expf(m1 - nm) + os * __expf(om - nm); m1 = nm;
            om = __shfl_xor(m2, off, 64); os = __shfl_xor(s2, off, 64);
            nm = fmaxf(m2, om); s2 = s2 * __expf(m2 - nm) + os * __expf(om - nm); m2 = nm;
            om = __shfl_xor(m3, off, 64); os = __shfl_xor(s3, off, 64);
            nm = fmaxf(m3, om); s3 = s3 * __expf(m3 - nm) + os * __expf(om - nm); m3 = nm;
        }
        float rd0 = 1.f / (s0 + 1e-16f), rd1 = 1.f / (s1 + 1e-16f);
        float rd2 = 1.f / (s2 + 1e-16f), rd3 = 1.f / (s3 + 1e-16f);
        for (int base = r0; base < r1; base += 64) {
            int cnt = min(64, r1 - base);
            float4 w4v = {0.f, 0.f, 0.f, 0.f};
            int sreg = 0;
            if (lane < cnt) {
                int p = base + lane;
                sreg = csr_src[p];
                uint2 ae2 = *(const uint2*)(ae16c + (size_t)p * 2);
                f16x2 aelo = bc16(ae2.x), aehi = bc16(ae2.y);
                float4 aj = *(const float4*)(aijJ + (size_t)sreg * 4);
                const uint4* ep16 = (const uint4*)(ea16_csr + (size_t)p * 8);
                uint4 ua = ep16[0], ub = ep16[1];
                *(uint4*)&eabuf[wid][lane][0] = ua;
                *(uint4*)&eabuf[wid][lane][4] = ub;
                float al0 = LEAKY(ai.x + (float)aelo[0] + aj.x);
                float al1 = LEAKY(ai.y + (float)aelo[1] + aj.y);
                float al2 = LEAKY(ai.z + (float)aehi[0] + aj.z);
                float al3 = LEAKY(ai.w + (float)aehi[1] + aj.w);
                w4v.x = __expf(al0 - m0) * rd0;
                w4v.y = __expf(al1 - m1) * rd1;
                w4v.z = __expf(al2 - m2) * rd2;
                w4v.w = __expf(al3 - m3) * rd3;
            } else {
                *(uint4*)&eabuf[wid][lane][0] = z4;
                *(uint4*)&eabuf[wid][lane][4] = z4;
            }
            *(float4*)&wbuf[wid][lane][0] = w4v;
            srcbuf[wid][lane] = (lane < cnt) ? sreg : 0;
            asm volatile("s_waitcnt lgkmcnt(0)" ::: "memory");
            int nch = (cnt + 15) >> 4;
            for (int c = 0; c < nch; c++) agg_chunk(c);
            asm volatile("s_waitcnt lgkmcnt(0)" ::: "memory");
        }
    }
#pragma unroll
    for (int tt = 0; tt < 16; tt++) {
        float v = acc[tt];
        v += __shfl_xor(v, 16, 64);
        v += __shfl_xor(v, 32, 64);
        acc[tt] = v;
    }
    f16* ag = aggr16 + (size_t)n * 256;
#pragma unroll
    for (int tt = 0; tt < 16; tt++)
        if ((tt >> 2) == g) ag[tt * 16 + ll] = (f16)acc[tt];
}

// MFMA k_post: celu(aggr16@WsP+b) -> GRU -> LayerNorm, fused next-step xp/aij.
// last=1: write final xc to out, skip xp/aij and the dead h_out store.
__global__ __launch_bounds__(256) void k_post(
    const f16* __restrict__ aggr16, const f16* __restrict__ WsP,
    const float* __restrict__ bvec, const float* __restrict__ h_in,
    float* __restrict__ h_out, const f16* __restrict__ WihP,
    const f16* __restrict__ WhhP, const float* __restrict__ bih,
    const float* __restrict__ bhh, const float* __restrict__ gamma,
    const float* __restrict__ beta, const f16* __restrict__ WnB,
    const f16* __restrict__ awB, f16* __restrict__ xp16,
    float* __restrict__ aijI, float* __restrict__ aijJ,
    float* __restrict__ xc_out, int last)
{
    __shared__ __align__(16) f16 m_lds[4][16][72];  // 18 KB, +8 pad
    int t = threadIdx.x, w = t >> 6, l = t & 63;
    int lg = l >> 4, ll = l & 15;
    int nb = blockIdx.x * 64 + w * 16;
    int nodeA = nb + ll;
    int nodeAc = nodeA < NNODES ? nodeA : NNODES - 1;

    f32x4 zero = {0.f, 0.f, 0.f, 0.f};
    f32x4 acc1[4];
#pragma unroll
    for (int tt = 0; tt < 4; tt++) acc1[tt] = zero;
    const f16x8* WsV = (const f16x8*)WsP;
#pragma unroll
    for (int ks = 0; ks < 8; ks++) {
        f16x8 a = *(const f16x8*)(aggr16 + (size_t)nodeAc * 256 + ks * 32 + lg * 8);
#pragma unroll
        for (int tt = 0; tt < 4; tt++) {
            f16x8 b = WsV[(ks * 4 + tt) * 64 + l];
            acc1[tt] = __builtin_amdgcn_mfma_f32_16x16x32_f16(a, b, acc1[tt], 0, 0, 0);
        }
    }
#pragma unroll
    for (int tt = 0; tt < 4; tt++) {
        float bj = bvec[tt * 16 + ll];
#pragma unroll
        for (int i = 0; i < 4; i++) {
            float v = acc1[tt][i] + bj;
            v = v > 0.f ? v : (__expf(v) - 1.f);  // celu
            m_lds[w][lg * 4 + i][tt * 16 + ll] = (f16)v;
        }
    }
    asm volatile("s_waitcnt lgkmcnt(0)" ::: "memory");

    f16x8 mf[2], hf[2];
#pragma unroll
    for (int ks = 0; ks < 2; ks++) {
        mf[ks] = *(const f16x8*)(&m_lds[w][ll][ks * 32 + lg * 8]);
        const float* hp = h_in + (size_t)nodeAc * 64 + ks * 32 + lg * 8;
        float4 h0 = *(const float4*)(hp);
        float4 h1 = *(const float4*)(hp + 4);
        f16x8 hh;
        hh[0] = (f16)h0.x; hh[1] = (f16)h0.y; hh[2] = (f16)h0.z; hh[3] = (f16)h0.w;
        hh[4] = (f16)h1.x; hh[5] = (f16)h1.y; hh[6] = (f16)h1.z; hh[7] = (f16)h1.w;
        hf[ks] = hh;
    }
    f32x4 accI[12], accH[12];
#pragma unroll
    for (int tt = 0; tt < 12; tt++) { accI[tt] = zero; accH[tt] = zero; }
    const f16x8* WiV = (const f16x8*)WihP;
    const f16x8* WhV = (const f16x8*)WhhP;
#pragma unroll
    for (int ks = 0; ks < 2; ks++) {
#pragma unroll
        for (int tt = 0; tt < 12; tt++) {
            f16x8 bi = WiV[(ks * 12 + tt) * 64 + l];
            accI[tt] = __builtin_amdgcn_mfma_f32_16x16x32_f16(mf[ks], bi, accI[tt], 0, 0, 0);
            f16x8 bh = WhV[(ks * 12 + tt) * 64 + l];
            accH[tt] = __builtin_amdgcn_mfma_f32_16x16x32_f16(hf[ks], bh, accH[tt], 0, 0, 0);
        }
    }

    float bI[12], bH[12];
#pragma unroll
    for (int tt = 0; tt < 12; tt++) {
        bI[tt] = bih[ll + 16 * tt];
        bH[tt] = bhh[ll + 16 * tt];
    }
    float ga[4], be[4];
#pragma unroll
    for (int u = 0; u < 4; u++) { ga[u] = gamma[ll + 16 * u]; be[u] = beta[ll + 16 * u]; }
    float hnew[4][4];
#pragma unroll
    for (int i = 0; i < 4; i++) {
        int node = nb + lg * 4 + i;
        int nc = node < NNODES ? node : NNODES - 1;
        const float* hrow = h_in + (size_t)nc * 64 + ll;
#pragma unroll
        for (int u = 0; u < 4; u++) {
            float hv = hrow[16 * u];
            float r = 1.f / (1.f + __expf(-(accI[u][i] + bI[u] + accH[u][i] + bH[u])));
            float z = 1.f / (1.f + __expf(-(accI[u + 4][i] + bI[u + 4] + accH[u + 4][i] + bH[u + 4])));
            float pre = accI[u + 8][i] + bI[u + 8] + r * (accH[u + 8][i] + bH[u + 8]);
            float e2 = __expf(2.f * pre);
            float nn = 1.f - 2.f / (e2 + 1.f);  // tanh, inf-safe
            hnew[i][u] = (1.f - z) * nn + z * hv;
        }
    }
#pragma unroll
    for (int i = 0; i < 4; i++) {
        float s = hnew[i][0] + hnew[i][1] + hnew[i][2] + hnew[i][3];
        float q = hnew[i][0] * hnew[i][0] + hnew[i][1] * hnew[i][1]
                + hnew[i][2] * hnew[i][2] + hnew[i][3] * hnew[i][3];
#pragma unroll
        for (int off = 1; off < 16; off <<= 1) {
            s += __shfl_xor(s, off, 64);
            q += __shfl_xor(q, off, 64);
        }
        float mu = s * (1.f / 64.f);
        float var = q * (1.f / 64.f) - mu * mu;
        float rstd = rsqrtf(var + 1e-5f);
        int node = nb + lg * 4 + i;
        bool ok = node < NNODES;
        float* ho = h_out + (size_t)node * 64 + ll;
        float* xo = xc_out + (size_t)node * 64 + ll;
#pragma unroll
        for (int u = 0; u < 4; u++) {
            float xcv = (hnew[i][u] - mu) * rstd * ga[u] + be[u];
            if (ok) {
                if (last) xo[16 * u] = xcv;
                else      ho[16 * u] = hnew[i][u];
            }
            m_lds[w][lg * 4 + i][16 * u + ll] = (f16)xcv;
        }
    }
    if (last) return;
    asm volatile("s_waitcnt lgkmcnt(0)" ::: "memory");

    // ---- fused next-step xp/aij ----
    f16x8 afr[2];
#pragma unroll
    for (int ks = 0; ks < 2; ks++)
        afr[ks] = *(const f16x8*)(&m_lds[w][ll][ks * 32 + lg * 8]);
    f32x4 c[16];
#pragma unroll
    for (int tt = 0; tt < 16; tt++) c[tt] = zero;
    f32x4 caw = zero;
    const f16x8* WnV = (const f16x8*)WnB;
    const f16x8* awV = (const f16x8*)awB;
#pragma unroll
    for (int ks = 0; ks < 2; ks++) {
        caw = __builtin_amdgcn_mfma_f32_16x16x32_f16(afr[ks], awV[ks * 64 + l], caw, 0, 0, 0);
#pragma unroll
        for (int tt = 0; tt < 16; tt++)
            c[tt] = __builtin_amdgcn_mfma_f32_16x16x32_f16(
                afr[ks], WnV[(ks * 16 + tt) * 64 + l], c[tt], 0, 0, 0);
    }
#pragma unroll
    for (int i = 0; i < 4; i++) {
        int node = nb + lg * 4 + i;
        if (node < NNODES) {
            f16x8 o0, o1;
#pragma unroll
            for (int tt = 0; tt < 8; tt++) o0[tt] = (f16)c[tt][i];
#pragma unroll
            for (int tt = 0; tt < 8; tt++) o1[tt] = (f16)c[8 + tt][i];
            f16* dstp = xp16 + (size_t)node * 256 + ll * 16;
            *(f16x8*)dstp = o0;
            *(f16x8*)(dstp + 8) = o1;
            if (ll < 4)      aijI[(size_t)node * 4 + ll] = caw[i];
            else if (ll < 8) aijJ[(size_t)node * 4 + (ll - 4)] = caw[i];
        }
    }
}

// ---------------- launcher ----------------

extern "C" void kernel_launch(void* const* d_in, const int* in_sizes, int n_in,
                              void* d_out, int out_size, void* d_ws, size_t ws_size,
                              hipStream_t stream)
{
    const float* x         = (const float*)d_in[0];
    const int*   edge_index= (const int*)d_in[1];
    const float* edge_attr = (const float*)d_in[2];
    const float* Wn        = (const float*)d_in[3];
    const float* We        = (const float*)d_in[4];
    const float* Wa        = (const float*)d_in[5];
    const float* Ws        = (const float*)d_in[6];
    const float* bv        = (const float*)d_in[7];
    const float* Wih       = (const float*)d_in[8];
    const float* Whh       = (const float*)d_in[9];
    const float* bih       = (const float*)d_in[10];
    const float* bhh       = (const float*)d_in[11];
    const float* gamma     = (const float*)d_in[12];
    const float* beta      = (const float*)d_in[13];
    float* out = (float*)d_out;

    const int* src = edge_index;
    const int* dst = edge_index + NEDGES;

    char* w = (char*)d_ws;
    auto alloc = [&](size_t bytes) {
        char* p = w;
        w += (bytes + 255) & ~(size_t)255;
        return p;
    };
    f16*   xp16     = (f16*)alloc((size_t)NNODES * 256 * 2);
    f16*   aggr16   = (f16*)alloc((size_t)NNODES * 256 * 2);
    uint*  ae16c    = (uint*)alloc((size_t)NEDGES * 2 * 4);
    uint*  ea16_csr = (uint*)alloc((size_t)NEDGES * 8 * 4);
    float* hbuf     = (float*)alloc((size_t)NNODES * 64 * 4);
    float* aijI     = (float*)alloc((size_t)NNODES * 4 * 4);
    float* aijJ     = (float*)alloc((size_t)NNODES * 4 * 4);
    int*   counts   = (int*)alloc((size_t)NNODES * 4);
    int*   rankv    = (int*)alloc((size_t)NEDGES * 4);
    int*   row_ptr  = (int*)alloc((size_t)(NNODES + 1) * 4);
    int*   csr_src  = (int*)alloc((size_t)NEDGES * 4);
    int*   psum     = (int*)alloc(64 * 4);
    float* wnwa0    = (float*)alloc(256 * 4);
    float* wnwa2    = (float*)alloc(256 * 4);
    float* wewa1    = (float*)alloc(64 * 4);
    f16*   WeB      = (f16*)alloc(1024 * 4 * 2);
    f16*   WsP      = (f16*)alloc(2048 * 8 * 2);
    f16*   WihP     = (f16*)alloc(1536 * 8 * 2);
    f16*   WhhP     = (f16*)alloc(1536 * 8 * 2);
    f16*   WnB      = (f16*)alloc(2048 * 8 * 2);
    f16*   awB      = (f16*)alloc(128 * 8 * 2);

    const int NSCAN = (NNODES + 1023) / 1024;   // 49

    k_fold1<<<1, 256, 0, stream>>>(Wn, We, Wa, wnwa0, wnwa2, wewa1);
    hipMemsetAsync(counts, 0, (size_t)NNODES * 4, stream);
    k_hist<<<NEDGES / 256, 256, 0, stream>>>(dst, counts, rankv);
    k_fold2<<<8, 256, 0, stream>>>(Wn, We, Wih, Whh, Ws, wnwa0, wnwa2,
                                   WeB, WsP, WihP, WhhP, WnB, awB);
    k_scan1<<<NSCAN, 1024, 0, stream>>>(counts, psum);
    k_scan0<<<1, 64, 0, stream>>>(psum, NSCAN);
    k_scan2<<<NSCAN, 1024, 0, stream>>>(counts, psum, row_ptr);
    k_scatter<<<NEDGES / 256, 256, 0, stream>>>(src, dst, rankv, edge_attr,
                                                wewa1, row_ptr, csr_src,
                                                ae16c, ea16_csr);

    k_xpaij<<<(NNODES + 63) / 64, 256, 0, stream>>>(x, WnB, awB,
                                                    xp16, aijI, aijJ);
    for (int step = 0; step < 3; step++) {
        const float* h_in = (step == 0) ? x : hbuf;
        k_node<<<NNODES / 4, 256, 0, stream>>>(row_ptr, csr_src, ae16c, aijI,
                                               aijJ, xp16, ea16_csr, WeB, aggr16);
        k_post<<<(NNODES + 63) / 64, 256, 0, stream>>>(
            aggr16, WsP, bv, h_in, hbuf, WihP, WhhP, bih, bhh, gamma, beta,
            WnB, awB, xp16, aijI, aijJ, out, step == 2 ? 1 : 0);
    }
}

// Round 18
// 490.512 us; speedup vs baseline: 1.2190x; 1.0424x over previous
//
#include <hip/hip_runtime.h>
#include <math.h>

#define NNODES 50000
#define NEDGES 800000
// DIM=64, EDGE_DIM=16, HEADS=4, HC=256

typedef _Float16 f16;
typedef _Float16 f16x2 __attribute__((ext_vector_type(2)));
typedef _Float16 f16x4 __attribute__((ext_vector_type(4)));
typedef _Float16 f16x8 __attribute__((ext_vector_type(8)));
typedef float f32x4 __attribute__((ext_vector_type(4)));

// guaranteed single-instruction f32 += f32 * f16(half of WRD)
#define FMAMIX_LO(ACC, PV, WRD) \
    asm("v_fma_mix_f32 %0, %1, %2, %0 op_sel_hi:[0,1,0]" \
        : "+v"(ACC) : "v"(PV), "v"(WRD))
#define FMAMIX_HI(ACC, PV, WRD) \
    asm("v_fma_mix_f32 %0, %1, %2, %0 op_sel:[0,1,0] op_sel_hi:[0,1,0]" \
        : "+v"(ACC) : "v"(PV), "v"(WRD))

__device__ inline uint pk16(float a, float b) {
    union { f16x2 h; uint u; } c;
    c.h[0] = (f16)a; c.h[1] = (f16)b;
    return c.u;
}
__device__ inline f16x2 bc16(uint u) {
    union { uint u; f16x2 h; } c; c.u = u; return c.h;
}
__device__ inline float wred_max(float v) {
#pragma unroll
    for (int off = 32; off; off >>= 1) v = fmaxf(v, __shfl_xor(v, off, 64));
    return v;
}
__device__ inline float wred_sum(float v) {
#pragma unroll
    for (int off = 32; off; off >>= 1) v += __shfl_xor(v, off, 64);
    return v;
}
__device__ inline float wred_max16(float v) {
#pragma unroll
    for (int off = 8; off; off >>= 1) v = fmaxf(v, __shfl_xor(v, off, 64));
    return v;
}
__device__ inline float wred_sum16(float v) {
#pragma unroll
    for (int off = 8; off; off >>= 1) v += __shfl_xor(v, off, 64);
    return v;
}

// ---------------- one-time prep kernels ----------------

__global__ __launch_bounds__(256) void k_fold1(
    const float* __restrict__ Wn, const float* __restrict__ We,
    const float* __restrict__ Wa,
    float* __restrict__ wnwa0, float* __restrict__ wnwa2,
    float* __restrict__ wewa1)
{
    int t = threadIdx.x;
    {
        int k = t >> 2, h = t & 3;
        float s0 = 0.f, s2 = 0.f;
        for (int c = 0; c < 64; c++) {
            float wn = Wn[k * 256 + h * 64 + c];
            s0 = fmaf(wn, Wa[h * 192 + c], s0);
            s2 = fmaf(wn, Wa[h * 192 + 128 + c], s2);
        }
        wnwa0[t] = s0;
        wnwa2[t] = s2;
    }
    if (t < 64) {
        int k = t >> 2, h = t & 3;
        float s1 = 0.f;
        for (int c = 0; c < 64; c++)
            s1 = fmaf(We[k * 256 + h * 64 + c], Wa[h * 192 + 64 + c], s1);
        wewa1[t] = s1;
    }
}

__global__ __launch_bounds__(256) void k_fold2(
    const float* __restrict__ Wn, const float* __restrict__ We,
    const float* __restrict__ Wih, const float* __restrict__ Whh,
    const float* __restrict__ Ws, const float* __restrict__ wnwa0,
    const float* __restrict__ wnwa2,
    f16* __restrict__ WeB, f16* __restrict__ WsP, f16* __restrict__ WihP,
    f16* __restrict__ WhhP, f16* __restrict__ WnB, f16* __restrict__ awB)
{
    int gid = blockIdx.x * 256 + threadIdx.x;
    const int STR = 8 * 256;
    for (int idx = gid; idx < 128; idx += STR) {
        int ks = idx >> 6, l = idx & 63;
        int lg = l >> 4, c = l & 15;
        f16* o = awB + (size_t)idx * 8;
        for (int j = 0; j < 8; j++) {
            int k = ks * 32 + lg * 8 + j;
            float v = (c < 4) ? wnwa0[k * 4 + c] : ((c < 8) ? wnwa2[k * 4 + (c - 4)] : 0.f);
            o[j] = (f16)v;
        }
    }
    for (int idx = gid; idx < 2048; idx += STR) {
        int l = idx & 63, tt = (idx >> 6) & 15, ks = idx >> 10;
        int lg = l >> 4, ll = l & 15;
        f16* o = WnB + (size_t)idx * 8;
        for (int j = 0; j < 8; j++)
            o[j] = (f16)Wn[(ks * 32 + lg * 8 + j) * 256 + tt * 16 + ll];
    }
    for (int idx = gid; idx < 1024; idx += STR) {
        int tt = idx >> 6, l = idx & 63;
        int lg = l >> 4, ll = l & 15;
        f16* o = WeB + (size_t)idx * 4;
        for (int j = 0; j < 4; j++)
            o[j] = (f16)We[(lg * 4 + j) * 256 + tt * 16 + ll];
    }
    for (int e = gid; e < 2048; e += STR) {
        int l = e & 63, tt = (e >> 6) & 3, ks = e >> 8;
        int lg = l >> 4, ll = l & 15;
        f16* o = WsP + (size_t)e * 8;
        for (int j = 0; j < 8; j++)
            o[j] = (f16)Ws[(ks * 32 + lg * 8 + j) * 64 + tt * 16 + ll];
    }
    for (int e = gid; e < 1536; e += STR) {
        int l = e & 63, q = e >> 6;
        int tt = q % 12, ks = q / 12;
        int lg = l >> 4, ll = l & 15;
        int outc = tt * 16 + ll;
        for (int j = 0; j < 8; j++) {
            int k = ks * 32 + lg * 8 + j;
            WihP[(size_t)e * 8 + j] = (f16)Wih[outc * 64 + k];
            WhhP[(size_t)e * 8 + j] = (f16)Whh[outc * 64 + k];
        }
    }
}

__global__ __launch_bounds__(256) void k_hist(const int* __restrict__ dst,
                                              int* __restrict__ counts,
                                              int* __restrict__ rankv)
{
    int e = blockIdx.x * 256 + threadIdx.x;
    rankv[e] = atomicAdd(&counts[dst[e]], 1);
}

__global__ __launch_bounds__(1024) void k_scan1(const int* __restrict__ counts,
                                                int* __restrict__ psum)
{
    __shared__ int wsum[16];
    int t = threadIdx.x, wid = t >> 6, lane = t & 63;
    int idx = blockIdx.x * 1024 + t;
    int c = (idx < NNODES) ? counts[idx] : 0;
    int v = c;
#pragma unroll
    for (int off = 32; off; off >>= 1) v += __shfl_xor(v, off, 64);
    if (lane == 0) wsum[wid] = v;
    __syncthreads();
    if (t == 0) {
        int s = 0;
        for (int wk = 0; wk < 16; wk++) s += wsum[wk];
        psum[blockIdx.x] = s;
    }
}

__global__ __launch_bounds__(64) void k_scan0(int* __restrict__ psum, int nb)
{
    if (threadIdx.x == 0) {
        int run = 0;
        for (int b = 0; b < nb; b++) { int s = psum[b]; psum[b] = run; run += s; }
    }
}

__global__ __launch_bounds__(1024) void k_scan2(const int* __restrict__ counts,
                                                const int* __restrict__ psum,
                                                int* __restrict__ row_ptr)
{
    __shared__ int wsum[16];
    int t = threadIdx.x, wid = t >> 6, lane = t & 63;
    int idx = blockIdx.x * 1024 + t;
    int c = (idx < NNODES) ? counts[idx] : 0;
    int v = c;
#pragma unroll
    for (int off = 1; off < 64; off <<= 1) {
        int u = __shfl_up(v, off, 64);
        if (lane >= off) v += u;
    }
    if (lane == 63) wsum[wid] = v;
    __syncthreads();
    int wpre = 0;
#pragma unroll
    for (int wk = 0; wk < 16; wk++) {
        int s = wsum[wk];
        if (wk < wid) wpre += s;
    }
    if (idx < NNODES) row_ptr[idx] = psum[blockIdx.x] + wpre + v - c;
    if (idx == 0) row_ptr[NNODES] = NEDGES;
}

__global__ __launch_bounds__(256) void k_scatter(
    const int* __restrict__ srcv, const int* __restrict__ dstv,
    const int* __restrict__ rankv,
    const float* __restrict__ ea, const float* __restrict__ wewa1,
    const int* __restrict__ row_ptr,
    int* __restrict__ csr_src, uint* __restrict__ ae16c,
    uint* __restrict__ ea16_csr)
{
    __shared__ float w[64];
    int t = threadIdx.x;
    if (t < 64) w[t] = wewa1[t];
    __syncthreads();
    int e = blockIdx.x * 256 + t;
    int d = dstv[e];
    int pos = row_ptr[d] + rankv[e];
    csr_src[pos] = srcv[e];
    const float4* p = (const float4*)(ea + (size_t)e * 16);
    float4 v0 = p[0], v1 = p[1], v2 = p[2], v3 = p[3];
    float eav[16] = {v0.x, v0.y, v0.z, v0.w, v1.x, v1.y, v1.z, v1.w,
                     v2.x, v2.y, v2.z, v2.w, v3.x, v3.y, v3.z, v3.w};
    float a0 = 0.f, a1 = 0.f, a2 = 0.f, a3 = 0.f;
#pragma unroll
    for (int k = 0; k < 16; k++) {
        a0 = fmaf(eav[k], w[k * 4 + 0], a0);
        a1 = fmaf(eav[k], w[k * 4 + 1], a1);
        a2 = fmaf(eav[k], w[k * 4 + 2], a2);
        a3 = fmaf(eav[k], w[k * 4 + 3], a3);
    }
    uint2 ae2; ae2.x = pk16(a0, a1); ae2.y = pk16(a2, a3);
    *(uint2*)(ae16c + (size_t)pos * 2) = ae2;
    uint4 pa, pb;
    pa.x = pk16(eav[0], eav[1]);  pa.y = pk16(eav[2], eav[3]);
    pa.z = pk16(eav[4], eav[5]);  pa.w = pk16(eav[6], eav[7]);
    pb.x = pk16(eav[8], eav[9]);  pb.y = pk16(eav[10], eav[11]);
    pb.z = pk16(eav[12], eav[13]); pb.w = pk16(eav[14], eav[15]);
    uint4* d16 = (uint4*)(ea16_csr + (size_t)pos * 8);
    d16[0] = pa; d16[1] = pb;
}

// ---------------- per-timestep kernels ----------------

// MFMA xp+aij from f32 node features (step 0 only), f16 xp.
__global__ __launch_bounds__(256) void k_xpaij(
    const float* __restrict__ xc, const f16* __restrict__ WnB,
    const f16* __restrict__ awB, f16* __restrict__ xp16,
    float* __restrict__ aijI, float* __restrict__ aijJ)
{
    int t = threadIdx.x, w = t >> 6, l = t & 63;
    int lg = l >> 4, ll = l & 15;
    int wbase = blockIdx.x * 64 + w * 16;
    int nodeA = wbase + ll;
    int nA = nodeA < NNODES ? nodeA : NNODES - 1;

    f16x8 afr[2];
#pragma unroll
    for (int ks = 0; ks < 2; ks++) {
        const float* xpr = xc + (size_t)nA * 64 + ks * 32 + lg * 8;
        float4 a0 = *(const float4*)xpr;
        float4 a1 = *(const float4*)(xpr + 4);
        f16x8 v;
        v[0] = (f16)a0.x; v[1] = (f16)a0.y; v[2] = (f16)a0.z; v[3] = (f16)a0.w;
        v[4] = (f16)a1.x; v[5] = (f16)a1.y; v[6] = (f16)a1.z; v[7] = (f16)a1.w;
        afr[ks] = v;
    }
    f32x4 zero = {0.f, 0.f, 0.f, 0.f};
    f32x4 c[16];
#pragma unroll
    for (int tt = 0; tt < 16; tt++) c[tt] = zero;
    f32x4 caw = zero;
    const f16x8* WnV = (const f16x8*)WnB;
    const f16x8* awV = (const f16x8*)awB;
#pragma unroll
    for (int ks = 0; ks < 2; ks++) {
        caw = __builtin_amdgcn_mfma_f32_16x16x32_f16(afr[ks], awV[ks * 64 + l], caw, 0, 0, 0);
#pragma unroll
        for (int tt = 0; tt < 16; tt++)
            c[tt] = __builtin_amdgcn_mfma_f32_16x16x32_f16(
                afr[ks], WnV[(ks * 16 + tt) * 64 + l], c[tt], 0, 0, 0);
    }
#pragma unroll
    for (int i = 0; i < 4; i++) {
        int node = wbase + lg * 4 + i;
        if (node < NNODES) {
            f16x8 o0, o1;
#pragma unroll
            for (int tt = 0; tt < 8; tt++) o0[tt] = (f16)c[tt][i];
#pragma unroll
            for (int tt = 0; tt < 8; tt++) o1[tt] = (f16)c[8 + tt][i];
            f16* dstp = xp16 + (size_t)node * 256 + ll * 16;
            *(f16x8*)dstp = o0;
            *(f16x8*)(dstp + 8) = o1;
            if (ll < 4)      aijI[(size_t)node * 4 + ll] = caw[i];
            else if (ll < 8) aijJ[(size_t)node * 4 + (ll - 4)] = caw[i];
        }
    }
}

#define LEAKY(v) ((v) > 0.f ? (v) : 0.2f * (v))

// Softmax + MFMA aggregation: one wave per dst node, 4 nodes/block.
// agg_chunk is the R15 single-pass form (32B gather, all 4 heads): the R17
// half-split cut VGPR 72->68 without crossing the 64 occupancy step and its
// serialized gathers cost ~6us -- reverted.
__global__ __launch_bounds__(256) void k_node(
    const int* __restrict__ row_ptr, const int* __restrict__ csr_src,
    const uint* __restrict__ ae16c, const float* __restrict__ aijI,
    const float* __restrict__ aijJ, const f16* __restrict__ xp16,
    const uint* __restrict__ ea16_csr, const f16* __restrict__ WeB,
    f16* __restrict__ aggr16)
{
    __shared__ float wbuf[4][64][4];
    __shared__ uint  eabuf[4][64][8];
    __shared__ int   srcbuf[4][64];
    int t = threadIdx.x, wid = t >> 6, lane = t & 63;
    int ll = lane & 15, g = lane >> 4;
    int n = blockIdx.x * 4 + wid;
    uint4 z4 = {0u, 0u, 0u, 0u};
    *(uint4*)&eabuf[wid][lane][0] = z4;
    *(uint4*)&eabuf[wid][lane][4] = z4;
    f16x4 wb[16];
#pragma unroll
    for (int tt = 0; tt < 16; tt++)
        wb[tt] = *(const f16x4*)(WeB + (size_t)(tt * 64 + lane) * 4);
    int r0 = row_ptr[n], r1 = row_ptr[n + 1];
    int deg = r1 - r0;
    float acc[16];
#pragma unroll
    for (int tt = 0; tt < 16; tt++) acc[tt] = 0.f;
    f32x4 zacc = {0.f, 0.f, 0.f, 0.f};

    auto agg_chunk = [&](int c) {
        int4 s4 = *(const int4*)&srcbuf[wid][c * 16 + g * 4];
        const f16* xr0 = xp16 + ((size_t)(uint)s4.x) * 256 + ll * 16;
        const f16* xr1 = xp16 + ((size_t)(uint)s4.y) * 256 + ll * 16;
        const f16* xr2 = xp16 + ((size_t)(uint)s4.z) * 256 + ll * 16;
        const f16* xr3 = xp16 + ((size_t)(uint)s4.w) * 256 + ll * 16;
        uint4 xA[4], xB[4];
        xA[0] = *(const uint4*)xr0; xB[0] = *(const uint4*)(xr0 + 8);
        xA[1] = *(const uint4*)xr1; xB[1] = *(const uint4*)(xr1 + 8);
        xA[2] = *(const uint4*)xr2; xB[2] = *(const uint4*)(xr2 + 8);
        xA[3] = *(const uint4*)xr3; xB[3] = *(const uint4*)(xr3 + 8);
        f16x4 eaf = *(const f16x4*)((const f16*)&eabuf[wid][c * 16 + ll][0] + g * 4);
        float4 w4 = *(const float4*)&wbuf[wid][c * 16 + ll][0];
        f16 av[4] = {(f16)w4.x, (f16)w4.y, (f16)w4.z, (f16)w4.w};
        f16x4 Ah[4];
#pragma unroll
        for (int h = 0; h < 4; h++)
#pragma unroll
            for (int j = 0; j < 4; j++)
                Ah[h][j] = eaf[j] * av[h];
#pragma unroll
        for (int h = 0; h < 4; h++) {
            f32x4 p0 = __builtin_amdgcn_mfma_f32_16x16x16f16(Ah[h], wb[h * 4 + 0], zacc, 0, 0, 0);
            f32x4 p1 = __builtin_amdgcn_mfma_f32_16x16x16f16(Ah[h], wb[h * 4 + 1], zacc, 0, 0, 0);
            f32x4 p2 = __builtin_amdgcn_mfma_f32_16x16x16f16(Ah[h], wb[h * 4 + 2], zacc, 0, 0, 0);
            f32x4 p3 = __builtin_amdgcn_mfma_f32_16x16x16f16(Ah[h], wb[h * 4 + 3], zacc, 0, 0, 0);
#pragma unroll
            for (int ttl = 0; ttl < 4; ttl++) {
                int tt = h * 4 + ttl;
                f32x4 pv = ttl == 0 ? p0 : (ttl == 1 ? p1 : (ttl == 2 ? p2 : p3));
                int q = tt & 7;
#pragma unroll
                for (int r = 0; r < 4; r++) {
                    uint4 xs = (tt < 8) ? xA[r] : xB[r];
                    uint wrd = (q >> 1) == 0 ? xs.x
                             : ((q >> 1) == 1 ? xs.y : ((q >> 1) == 2 ? xs.z : xs.w));
                    float pvf = pv[r];
                    if (q & 1) FMAMIX_HI(acc[tt], pvf, wrd);
                    else       FMAMIX_LO(acc[tt], pvf, wrd);
                }
            }
        }
    };

    if (deg > 0 && deg <= 64) {
        float4 ai = *(const float4*)(aijI + (size_t)n * 4);
        float al0 = -1e30f, al1 = -1e30f, al2 = -1e30f, al3 = -1e30f;
        int sreg = 0;
        if (lane < deg) {
            int p = r0 + lane;
            sreg = csr_src[p];
            uint2 ae2 = *(const uint2*)(ae16c + (size_t)p * 2);
            f16x2 aelo = bc16(ae2.x), aehi = bc16(ae2.y);
            float4 aj = *(const float4*)(aijJ + (size_t)sreg * 4);
            const uint4* ep16 = (const uint4*)(ea16_csr + (size_t)p * 8);
            uint4 ua = ep16[0], ub = ep16[1];
            *(uint4*)&eabuf[wid][lane][0] = ua;
            *(uint4*)&eabuf[wid][lane][4] = ub;
            al0 = LEAKY(ai.x + (float)aelo[0] + aj.x);
            al1 = LEAKY(ai.y + (float)aelo[1] + aj.y);
            al2 = LEAKY(ai.z + (float)aehi[0] + aj.z);
            al3 = LEAKY(ai.w + (float)aehi[1] + aj.w);
        }
        srcbuf[wid][lane] = (lane < deg) ? sreg : 0;
        float m0, m1, m2, m3, s0, s1, s2, s3;
        float p0, p1, p2, p3;
        if (deg <= 16) {
            m0 = wred_max16(al0); m1 = wred_max16(al1);
            m2 = wred_max16(al2); m3 = wred_max16(al3);
            p0 = (lane < deg) ? __expf(al0 - m0) : 0.f;
            p1 = (lane < deg) ? __expf(al1 - m1) : 0.f;
            p2 = (lane < deg) ? __expf(al2 - m2) : 0.f;
            p3 = (lane < deg) ? __expf(al3 - m3) : 0.f;
            s0 = wred_sum16(p0); s1 = wred_sum16(p1);
            s2 = wred_sum16(p2); s3 = wred_sum16(p3);
        } else {
            m0 = wred_max(al0); m1 = wred_max(al1);
            m2 = wred_max(al2); m3 = wred_max(al3);
            p0 = (lane < deg) ? __expf(al0 - m0) : 0.f;
            p1 = (lane < deg) ? __expf(al1 - m1) : 0.f;
            p2 = (lane < deg) ? __expf(al2 - m2) : 0.f;
            p3 = (lane < deg) ? __expf(al3 - m3) : 0.f;
            s0 = wred_sum(p0); s1 = wred_sum(p1);
            s2 = wred_sum(p2); s3 = wred_sum(p3);
        }
        float4 w4v;
        w4v.x = p0 * (1.f / (s0 + 1e-16f));
        w4v.y = p1 * (1.f / (s1 + 1e-16f));
        w4v.z = p2 * (1.f / (s2 + 1e-16f));
        w4v.w = p3 * (1.f / (s3 + 1e-16f));
        *(float4*)&wbuf[wid][lane][0] = w4v;
        asm volatile("s_waitcnt lgkmcnt(0)" ::: "memory");
        int nch = (deg + 15) >> 4;
        for (int c = 0; c < nch; c++) agg_chunk(c);
    } else if (deg > 0) {
        float4 ai = *(const float4*)(aijI + (size_t)n * 4);
        float m0 = -1e30f, m1 = -1e30f, m2 = -1e30f, m3 = -1e30f;
        float s0 = 0.f, s1 = 0.f, s2 = 0.f, s3 = 0.f;
        for (int base = r0; base < r1; base += 64) {
            int p = base + lane;
            if (p < r1) {
                int s = csr_src[p];
                uint2 ae2 = *(const uint2*)(ae16c + (size_t)p * 2);
                f16x2 aelo = bc16(ae2.x), aehi = bc16(ae2.y);
                float4 aj = *(const float4*)(aijJ + (size_t)s * 4);
                float al0 = LEAKY(ai.x + (float)aelo[0] + aj.x);
                float al1 = LEAKY(ai.y + (float)aelo[1] + aj.y);
                float al2 = LEAKY(ai.z + (float)aehi[0] + aj.z);
                float al3 = LEAKY(ai.w + (float)aehi[1] + aj.w);
                float nm;
                nm = fmaxf(m0, al0); s0 = s0 * __expf(m0 - nm) + __expf(al0 - nm); m0 = nm;
                nm = fmaxf(m1, al1); s1 = s1 * __expf(m1 - nm) + __expf(al1 - nm); m1 = nm;
                nm = fmaxf(m2, al2); s2 = s2 * __expf(m2 - nm) + __expf(al2 - nm); m2 = nm;
                nm = fmaxf(m3, al3); s3 = s3 * __expf(m3 - nm) + __expf(al3 - nm); m3 = nm;
            }
        }
#pragma unroll
        for (int off = 32; off; off >>= 1) {
            float om, os, nm;
            om = __shfl_xor(m0, off, 64); os = __shfl_xor(s0, off, 64);
            nm = fmaxf(m0, om); s0 = s0 * __expf(m0 - nm) + os * __expf(om - nm); m0 = nm;
            om = __shfl_xor(m1, off, 64); os = __shfl_xor(s1, off, 64);
            nm = fmaxf(m1, om); s1 = s1 * __expf(m1 - nm) + os * __expf(om - nm); m1 = nm;
            om = __shfl_xor(m2, off, 64); os = __shfl_xor(s2, off, 64);
            nm = fmaxf(m2, om); s2 = s2 * __expf(m2 - nm) + os * __expf(om - nm); m2 = nm;
            om = __shfl_xor(m3, off, 64); os = __shfl_xor(s3, off, 64);
            nm = fmaxf(m3, om); s3 = s3 * __expf(m3 - nm) + os * __expf(om - nm); m3 = nm;
        }
        float rd0 = 1.f / (s0 + 1e-16f), rd1 = 1.f / (s1 + 1e-16f);
        float rd2 = 1.f / (s2 + 1e-16f), rd3 = 1.f / (s3 + 1e-16f);
        for (int base = r0; base < r1; base += 64) {
            int cnt = min(64, r1 - base);
            float4 w4v = {0.f, 0.f, 0.f, 0.f};
            int sreg = 0;
            if (lane < cnt) {
                int p = base + lane;
                sreg = csr_src[p];
                uint2 ae2 = *(const uint2*)(ae16c + (size_t)p * 2);
                f16x2 aelo = bc16(ae2.x), aehi = bc16(ae2.y);
                float4 aj = *(const float4*)(aijJ + (size_t)sreg * 4);
                const uint4* ep16 = (const uint4*)(ea16_csr + (size_t)p * 8);
                uint4 ua = ep16[0], ub = ep16[1];
                *(uint4*)&eabuf[wid][lane][0] = ua;
                *(uint4*)&eabuf[wid][lane][4] = ub;
                float al0 = LEAKY(ai.x + (float)aelo[0] + aj.x);
                float al1 = LEAKY(ai.y + (float)aelo[1] + aj.y);
                float al2 = LEAKY(ai.z + (float)aehi[0] + aj.z);
                float al3 = LEAKY(ai.w + (float)aehi[1] + aj.w);
                w4v.x = __expf(al0 - m0) * rd0;
                w4v.y = __expf(al1 - m1) * rd1;
                w4v.z = __expf(al2 - m2) * rd2;
                w4v.w = __expf(al3 - m3) * rd3;
            } else {
                *(uint4*)&eabuf[wid][lane][0] = z4;
                *(uint4*)&eabuf[wid][lane][4] = z4;
            }
            *(float4*)&wbuf[wid][lane][0] = w4v;
            srcbuf[wid][lane] = (lane < cnt) ? sreg : 0;
            asm volatile("s_waitcnt lgkmcnt(0)" ::: "memory");
            int nch = (cnt + 15) >> 4;
            for (int c = 0; c < nch; c++) agg_chunk(c);
            asm volatile("s_waitcnt lgkmcnt(0)" ::: "memory");
        }
    }
#pragma unroll
    for (int tt = 0; tt < 16; tt++) {
        float v = acc[tt];
        v += __shfl_xor(v, 16, 64);
        v += __shfl_xor(v, 32, 64);
        acc[tt] = v;
    }
    f16* ag = aggr16 + (size_t)n * 256;
#pragma unroll
    for (int tt = 0; tt < 16; tt++)
        if ((tt >> 2) == g) ag[tt * 16 + ll] = (f16)acc[tt];
}

// MFMA k_post: celu(aggr16@WsP+b) -> GRU -> LayerNorm, fused next-step xp/aij.
// last=1: write final xc to out, skip xp/aij and the dead h_out store.
__global__ __launch_bounds__(256) void k_post(
    const f16* __restrict__ aggr16, const f16* __restrict__ WsP,
    const float* __restrict__ bvec, const float* __restrict__ h_in,
    float* __restrict__ h_out, const f16* __restrict__ WihP,
    const f16* __restrict__ WhhP, const float* __restrict__ bih,
    const float* __restrict__ bhh, const float* __restrict__ gamma,
    const float* __restrict__ beta, const f16* __restrict__ WnB,
    const f16* __restrict__ awB, f16* __restrict__ xp16,
    float* __restrict__ aijI, float* __restrict__ aijJ,
    float* __restrict__ xc_out, int last)
{
    __shared__ __align__(16) f16 m_lds[4][16][72];  // 18 KB, +8 pad
    int t = threadIdx.x, w = t >> 6, l = t & 63;
    int lg = l >> 4, ll = l & 15;
    int nb = blockIdx.x * 64 + w * 16;
    int nodeA = nb + ll;
    int nodeAc = nodeA < NNODES ? nodeA : NNODES - 1;

    f32x4 zero = {0.f, 0.f, 0.f, 0.f};
    f32x4 acc1[4];
#pragma unroll
    for (int tt = 0; tt < 4; tt++) acc1[tt] = zero;
    const f16x8* WsV = (const f16x8*)WsP;
#pragma unroll
    for (int ks = 0; ks < 8; ks++) {
        f16x8 a = *(const f16x8*)(aggr16 + (size_t)nodeAc * 256 + ks * 32 + lg * 8);
#pragma unroll
        for (int tt = 0; tt < 4; tt++) {
            f16x8 b = WsV[(ks * 4 + tt) * 64 + l];
            acc1[tt] = __builtin_amdgcn_mfma_f32_16x16x32_f16(a, b, acc1[tt], 0, 0, 0);
        }
    }
#pragma unroll
    for (int tt = 0; tt < 4; tt++) {
        float bj = bvec[tt * 16 + ll];
#pragma unroll
        for (int i = 0; i < 4; i++) {
            float v = acc1[tt][i] + bj;
            v = v > 0.f ? v : (__expf(v) - 1.f);  // celu
            m_lds[w][lg * 4 + i][tt * 16 + ll] = (f16)v;
        }
    }
    asm volatile("s_waitcnt lgkmcnt(0)" ::: "memory");

    f16x8 mf[2], hf[2];
#pragma unroll
    for (int ks = 0; ks < 2; ks++) {
        mf[ks] = *(const f16x8*)(&m_lds[w][ll][ks * 32 + lg * 8]);
        const float* hp = h_in + (size_t)nodeAc * 64 + ks * 32 + lg * 8;
        float4 h0 = *(const float4*)(hp);
        float4 h1 = *(const float4*)(hp + 4);
        f16x8 hh;
        hh[0] = (f16)h0.x; hh[1] = (f16)h0.y; hh[2] = (f16)h0.z; hh[3] = (f16)h0.w;
        hh[4] = (f16)h1.x; hh[5] = (f16)h1.y; hh[6] = (f16)h1.z; hh[7] = (f16)h1.w;
        hf[ks] = hh;
    }
    f32x4 accI[12], accH[12];
#pragma unroll
    for (int tt = 0; tt < 12; tt++) { accI[tt] = zero; accH[tt] = zero; }
    const f16x8* WiV = (const f16x8*)WihP;
    const f16x8* WhV = (const f16x8*)WhhP;
#pragma unroll
    for (int ks = 0; ks < 2; ks++) {
#pragma unroll
        for (int tt = 0; tt < 12; tt++) {
            f16x8 bi = WiV[(ks * 12 + tt) * 64 + l];
            accI[tt] = __builtin_amdgcn_mfma_f32_16x16x32_f16(mf[ks], bi, accI[tt], 0, 0, 0);
            f16x8 bh = WhV[(ks * 12 + tt) * 64 + l];
            accH[tt] = __builtin_amdgcn_mfma_f32_16x16x32_f16(hf[ks], bh, accH[tt], 0, 0, 0);
        }
    }

    float bI[12], bH[12];
#pragma unroll
    for (int tt = 0; tt < 12; tt++) {
        bI[tt] = bih[ll + 16 * tt];
        bH[tt] = bhh[ll + 16 * tt];
    }
    float ga[4], be[4];
#pragma unroll
    for (int u = 0; u < 4; u++) { ga[u] = gamma[ll + 16 * u]; be[u] = beta[ll + 16 * u]; }
    float hnew[4][4];
#pragma unroll
    for (int i = 0; i < 4; i++) {
        int node = nb + lg * 4 + i;
        int nc = node < NNODES ? node : NNODES - 1;
        const float* hrow = h_in + (size_t)nc * 64 + ll;
#pragma unroll
        for (int u = 0; u < 4; u++) {
            float hv = hrow[16 * u];
            float r = 1.f / (1.f + __expf(-(accI[u][i] + bI[u] + accH[u][i] + bH[u])));
            float z = 1.f / (1.f + __expf(-(accI[u + 4][i] + bI[u + 4] + accH[u + 4][i] + bH[u + 4])));
            float pre = accI[u + 8][i] + bI[u + 8] + r * (accH[u + 8][i] + bH[u + 8]);
            float e2 = __expf(2.f * pre);
            float nn = 1.f - 2.f / (e2 + 1.f);  // tanh, inf-safe
            hnew[i][u] = (1.f - z) * nn + z * hv;
        }
    }
#pragma unroll
    for (int i = 0; i < 4; i++) {
        float s = hnew[i][0] + hnew[i][1] + hnew[i][2] + hnew[i][3];
        float q = hnew[i][0] * hnew[i][0] + hnew[i][1] * hnew[i][1]
                + hnew[i][2] * hnew[i][2] + hnew[i][3] * hnew[i][3];
#pragma unroll
        for (int off = 1; off < 16; off <<= 1) {
            s += __shfl_xor(s, off, 64);
            q += __shfl_xor(q, off, 64);
        }
        float mu = s * (1.f / 64.f);
        float var = q * (1.f / 64.f) - mu * mu;
        float rstd = rsqrtf(var + 1e-5f);
        int node = nb + lg * 4 + i;
        bool ok = node < NNODES;
        float* ho = h_out + (size_t)node * 64 + ll;
        float* xo = xc_out + (size_t)node * 64 + ll;
#pragma unroll
        for (int u = 0; u < 4; u++) {
            float xcv = (hnew[i][u] - mu) * rstd * ga[u] + be[u];
            if (ok) {
                if (last) xo[16 * u] = xcv;
                else      ho[16 * u] = hnew[i][u];
            }
            m_lds[w][lg * 4 + i][16 * u + ll] = (f16)xcv;
        }
    }
    if (last) return;
    asm volatile("s_waitcnt lgkmcnt(0)" ::: "memory");

    // ---- fused next-step xp/aij ----
    f16x8 afr[2];
#pragma unroll
    for (int ks = 0; ks < 2; ks++)
        afr[ks] = *(const f16x8*)(&m_lds[w][ll][ks * 32 + lg * 8]);
    f32x4 c[16];
#pragma unroll
    for (int tt = 0; tt < 16; tt++) c[tt] = zero;
    f32x4 caw = zero;
    const f16x8* WnV = (const f16x8*)WnB;
    const f16x8* awV = (const f16x8*)awB;
#pragma unroll
    for (int ks = 0; ks < 2; ks++) {
        caw = __builtin_amdgcn_mfma_f32_16x16x32_f16(afr[ks], awV[ks * 64 + l], caw, 0, 0, 0);
#pragma unroll
        for (int tt = 0; tt < 16; tt++)
            c[tt] = __builtin_amdgcn_mfma_f32_16x16x32_f16(
                afr[ks], WnV[(ks * 16 + tt) * 64 + l], c[tt], 0, 0, 0);
    }
#pragma unroll
    for (int i = 0; i < 4; i++) {
        int node = nb + lg * 4 + i;
        if (node < NNODES) {
            f16x8 o0, o1;
#pragma unroll
            for (int tt = 0; tt < 8; tt++) o0[tt] = (f16)c[tt][i];
#pragma unroll
            for (int tt = 0; tt < 8; tt++) o1[tt] = (f16)c[8 + tt][i];
            f16* dstp = xp16 + (size_t)node * 256 + ll * 16;
            *(f16x8*)dstp = o0;
            *(f16x8*)(dstp + 8) = o1;
            if (ll < 4)      aijI[(size_t)node * 4 + ll] = caw[i];
            else if (ll < 8) aijJ[(size_t)node * 4 + (ll - 4)] = caw[i];
        }
    }
}

// ---------------- launcher ----------------

extern "C" void kernel_launch(void* const* d_in, const int* in_sizes, int n_in,
                              void* d_out, int out_size, void* d_ws, size_t ws_size,
                              hipStream_t stream)
{
    const float* x         = (const float*)d_in[0];
    const int*   edge_index= (const int*)d_in[1];
    const float* edge_attr = (const float*)d_in[2];
    const float* Wn        = (const float*)d_in[3];
    const float* We        = (const float*)d_in[4];
    const float* Wa        = (const float*)d_in[5];
    const float* Ws        = (const float*)d_in[6];
    const float* bv        = (const float*)d_in[7];
    const float* Wih       = (const float*)d_in[8];
    const float* Whh       = (const float*)d_in[9];
    const float* bih       = (const float*)d_in[10];
    const float* bhh       = (const float*)d_in[11];
    const float* gamma     = (const float*)d_in[12];
    const float* beta      = (const float*)d_in[13];
    float* out = (float*)d_out;

    const int* src = edge_index;
    const int* dst = edge_index + NEDGES;

    char* w = (char*)d_ws;
    auto alloc = [&](size_t bytes) {
        char* p = w;
        w += (bytes + 255) & ~(size_t)255;
        return p;
    };
    f16*   xp16     = (f16*)alloc((size_t)NNODES * 256 * 2);
    f16*   aggr16   = (f16*)alloc((size_t)NNODES * 256 * 2);
    uint*  ae16c    = (uint*)alloc((size_t)NEDGES * 2 * 4);
    uint*  ea16_csr = (uint*)alloc((size_t)NEDGES * 8 * 4);
    float* hbuf     = (float*)alloc((size_t)NNODES * 64 * 4);
    float* aijI     = (float*)alloc((size_t)NNODES * 4 * 4);
    float* aijJ     = (float*)alloc((size_t)NNODES * 4 * 4);
    int*   counts   = (int*)alloc((size_t)NNODES * 4);
    int*   rankv    = (int*)alloc((size_t)NEDGES * 4);
    int*   row_ptr  = (int*)alloc((size_t)(NNODES + 1) * 4);
    int*   csr_src  = (int*)alloc((size_t)NEDGES * 4);
    int*   psum     = (int*)alloc(64 * 4);
    float* wnwa0    = (float*)alloc(256 * 4);
    float* wnwa2    = (float*)alloc(256 * 4);
    float* wewa1    = (float*)alloc(64 * 4);
    f16*   WeB      = (f16*)alloc(1024 * 4 * 2);
    f16*   WsP      = (f16*)alloc(2048 * 8 * 2);
    f16*   WihP     = (f16*)alloc(1536 * 8 * 2);
    f16*   WhhP     = (f16*)alloc(1536 * 8 * 2);
    f16*   WnB      = (f16*)alloc(2048 * 8 * 2);
    f16*   awB      = (f16*)alloc(128 * 8 * 2);

    const int NSCAN = (NNODES + 1023) / 1024;   // 49

    k_fold1<<<1, 256, 0, stream>>>(Wn, We, Wa, wnwa0, wnwa2, wewa1);
    hipMemsetAsync(counts, 0, (size_t)NNODES * 4, stream);
    k_hist<<<NEDGES / 256, 256, 0, stream>>>(dst, counts, rankv);
    k_fold2<<<8, 256, 0, stream>>>(Wn, We, Wih, Whh, Ws, wnwa0, wnwa2,
                                   WeB, WsP, WihP, WhhP, WnB, awB);
    k_scan1<<<NSCAN, 1024, 0, stream>>>(counts, psum);
    k_scan0<<<1, 64, 0, stream>>>(psum, NSCAN);
    k_scan2<<<NSCAN, 1024, 0, stream>>>(counts, psum, row_ptr);
    k_scatter<<<NEDGES / 256, 256, 0, stream>>>(src, dst, rankv, edge_attr,
                                                wewa1, row_ptr, csr_src,
                                                ae16c, ea16_csr);

    k_xpaij<<<(NNODES + 63) / 64, 256, 0, stream>>>(x, WnB, awB,
                                                    xp16, aijI, aijJ);
    for (int step = 0; step < 3; step++) {
        const float* h_in = (step == 0) ? x : hbuf;
        k_node<<<NNODES / 4, 256, 0, stream>>>(row_ptr, csr_src, ae16c, aijI,
                                               aijJ, xp16, ea16_csr, WeB, aggr16);
        k_post<<<(NNODES + 63) / 64, 256, 0, stream>>>(
            aggr16, WsP, bv, h_in, hbuf, WihP, WhhP, bih, bhh, gamma, beta,
            WnB, awB, xp16, aijI, aijJ, out, step == 2 ? 1 : 0);
    }
}

// Round 20
// 490.359 us; speedup vs baseline: 1.2194x; 1.0003x over previous
//
#include <hip/hip_runtime.h>
#include <math.h>

#define NNODES 50000
#define NEDGES 800000
// DIM=64, EDGE_DIM=16, HEADS=4, HC=256

typedef _Float16 f16;
typedef _Float16 f16x2 __attribute__((ext_vector_type(2)));
typedef _Float16 f16x4 __attribute__((ext_vector_type(4)));
typedef _Float16 f16x8 __attribute__((ext_vector_type(8)));
typedef float f32x4 __attribute__((ext_vector_type(4)));

// guaranteed single-instruction f32 += f32 * f16(half of WRD)
#define FMAMIX_LO(ACC, PV, WRD) \
    asm("v_fma_mix_f32 %0, %1, %2, %0 op_sel_hi:[0,1,0]" \
        : "+v"(ACC) : "v"(PV), "v"(WRD))
#define FMAMIX_HI(ACC, PV, WRD) \
    asm("v_fma_mix_f32 %0, %1, %2, %0 op_sel:[0,1,0] op_sel_hi:[0,1,0]" \
        : "+v"(ACC) : "v"(PV), "v"(WRD))

__device__ inline uint pk16(float a, float b) {
    union { f16x2 h; uint u; } c;
    c.h[0] = (f16)a; c.h[1] = (f16)b;
    return c.u;
}
__device__ inline f16x2 bc16(uint u) {
    union { uint u; f16x2 h; } c; c.u = u; return c.h;
}
__device__ inline float wred_max(float v) {
#pragma unroll
    for (int off = 32; off; off >>= 1) v = fmaxf(v, __shfl_xor(v, off, 64));
    return v;
}
__device__ inline float wred_sum(float v) {
#pragma unroll
    for (int off = 32; off; off >>= 1) v += __shfl_xor(v, off, 64);
    return v;
}
__device__ inline float wred_max16(float v) {
#pragma unroll
    for (int off = 8; off; off >>= 1) v = fmaxf(v, __shfl_xor(v, off, 64));
    return v;
}
__device__ inline float wred_sum16(float v) {
#pragma unroll
    for (int off = 8; off; off >>= 1) v += __shfl_xor(v, off, 64);
    return v;
}

// ---------------- one-time prep kernels ----------------

__global__ __launch_bounds__(256) void k_fold1(
    const float* __restrict__ Wn, const float* __restrict__ We,
    const float* __restrict__ Wa,
    float* __restrict__ wnwa0, float* __restrict__ wnwa2,
    float* __restrict__ wewa1)
{
    int t = threadIdx.x;
    {
        int k = t >> 2, h = t & 3;
        float s0 = 0.f, s2 = 0.f;
        for (int c = 0; c < 64; c++) {
            float wn = Wn[k * 256 + h * 64 + c];
            s0 = fmaf(wn, Wa[h * 192 + c], s0);
            s2 = fmaf(wn, Wa[h * 192 + 128 + c], s2);
        }
        wnwa0[t] = s0;
        wnwa2[t] = s2;
    }
    if (t < 64) {
        int k = t >> 2, h = t & 3;
        float s1 = 0.f;
        for (int c = 0; c < 64; c++)
            s1 = fmaf(We[k * 256 + h * 64 + c], Wa[h * 192 + 64 + c], s1);
        wewa1[t] = s1;
    }
}

__global__ __launch_bounds__(256) void k_fold2(
    const float* __restrict__ Wn, const float* __restrict__ We,
    const float* __restrict__ Wih, const float* __restrict__ Whh,
    const float* __restrict__ Ws, const float* __restrict__ wnwa0,
    const float* __restrict__ wnwa2,
    f16* __restrict__ WeB, f16* __restrict__ WsP, f16* __restrict__ WihP,
    f16* __restrict__ WhhP, f16* __restrict__ WnB, f16* __restrict__ awB)
{
    int gid = blockIdx.x * 256 + threadIdx.x;
    const int STR = 8 * 256;
    for (int idx = gid; idx < 128; idx += STR) {
        int ks = idx >> 6, l = idx & 63;
        int lg = l >> 4, c = l & 15;
        f16* o = awB + (size_t)idx * 8;
        for (int j = 0; j < 8; j++) {
            int k = ks * 32 + lg * 8 + j;
            float v = (c < 4) ? wnwa0[k * 4 + c] : ((c < 8) ? wnwa2[k * 4 + (c - 4)] : 0.f);
            o[j] = (f16)v;
        }
    }
    for (int idx = gid; idx < 2048; idx += STR) {
        int l = idx & 63, tt = (idx >> 6) & 15, ks = idx >> 10;
        int lg = l >> 4, ll = l & 15;
        f16* o = WnB + (size_t)idx * 8;
        for (int j = 0; j < 8; j++)
            o[j] = (f16)Wn[(ks * 32 + lg * 8 + j) * 256 + tt * 16 + ll];
    }
    for (int idx = gid; idx < 1024; idx += STR) {
        int tt = idx >> 6, l = idx & 63;
        int lg = l >> 4, ll = l & 15;
        f16* o = WeB + (size_t)idx * 4;
        for (int j = 0; j < 4; j++)
            o[j] = (f16)We[(lg * 4 + j) * 256 + tt * 16 + ll];
    }
    for (int e = gid; e < 2048; e += STR) {
        int l = e & 63, tt = (e >> 6) & 3, ks = e >> 8;
        int lg = l >> 4, ll = l & 15;
        f16* o = WsP + (size_t)e * 8;
        for (int j = 0; j < 8; j++)
            o[j] = (f16)Ws[(ks * 32 + lg * 8 + j) * 64 + tt * 16 + ll];
    }
    for (int e = gid; e < 1536; e += STR) {
        int l = e & 63, q = e >> 6;
        int tt = q % 12, ks = q / 12;
        int lg = l >> 4, ll = l & 15;
        int outc = tt * 16 + ll;
        for (int j = 0; j < 8; j++) {
            int k = ks * 32 + lg * 8 + j;
            WihP[(size_t)e * 8 + j] = (f16)Wih[outc * 64 + k];
            WhhP[(size_t)e * 8 + j] = (f16)Whh[outc * 64 + k];
        }
    }
}

__global__ __launch_bounds__(256) void k_hist(const int* __restrict__ dst,
                                              int* __restrict__ counts,
                                              int* __restrict__ rankv)
{
    int e = blockIdx.x * 256 + threadIdx.x;
    rankv[e] = atomicAdd(&counts[dst[e]], 1);
}

__global__ __launch_bounds__(1024) void k_scan1(const int* __restrict__ counts,
                                                int* __restrict__ psum)
{
    __shared__ int wsum[16];
    int t = threadIdx.x, wid = t >> 6, lane = t & 63;
    int idx = blockIdx.x * 1024 + t;
    int c = (idx < NNODES) ? counts[idx] : 0;
    int v = c;
#pragma unroll
    for (int off = 32; off; off >>= 1) v += __shfl_xor(v, off, 64);
    if (lane == 0) wsum[wid] = v;
    __syncthreads();
    if (t == 0) {
        int s = 0;
        for (int wk = 0; wk < 16; wk++) s += wsum[wk];
        psum[blockIdx.x] = s;
    }
}

__global__ __launch_bounds__(64) void k_scan0(int* __restrict__ psum, int nb)
{
    if (threadIdx.x == 0) {
        int run = 0;
        for (int b = 0; b < nb; b++) { int s = psum[b]; psum[b] = run; run += s; }
    }
}

__global__ __launch_bounds__(1024) void k_scan2(const int* __restrict__ counts,
                                                const int* __restrict__ psum,
                                                int* __restrict__ row_ptr)
{
    __shared__ int wsum[16];
    int t = threadIdx.x, wid = t >> 6, lane = t & 63;
    int idx = blockIdx.x * 1024 + t;
    int c = (idx < NNODES) ? counts[idx] : 0;
    int v = c;
#pragma unroll
    for (int off = 1; off < 64; off <<= 1) {
        int u = __shfl_up(v, off, 64);
        if (lane >= off) v += u;
    }
    if (lane == 63) wsum[wid] = v;
    __syncthreads();
    int wpre = 0;
#pragma unroll
    for (int wk = 0; wk < 16; wk++) {
        int s = wsum[wk];
        if (wk < wid) wpre += s;
    }
    if (idx < NNODES) row_ptr[idx] = psum[blockIdx.x] + wpre + v - c;
    if (idx == 0) row_ptr[NNODES] = NEDGES;
}

__global__ __launch_bounds__(256) void k_scatter(
    const int* __restrict__ srcv, const int* __restrict__ dstv,
    const int* __restrict__ rankv,
    const float* __restrict__ ea, const float* __restrict__ wewa1,
    const int* __restrict__ row_ptr,
    int* __restrict__ csr_src, uint* __restrict__ ae16c,
    uint* __restrict__ ea16_csr)
{
    __shared__ float w[64];
    int t = threadIdx.x;
    if (t < 64) w[t] = wewa1[t];
    __syncthreads();
    int e = blockIdx.x * 256 + t;
    int d = dstv[e];
    int pos = row_ptr[d] + rankv[e];
    csr_src[pos] = srcv[e];
    const float4* p = (const float4*)(ea + (size_t)e * 16);
    float4 v0 = p[0], v1 = p[1], v2 = p[2], v3 = p[3];
    float eav[16] = {v0.x, v0.y, v0.z, v0.w, v1.x, v1.y, v1.z, v1.w,
                     v2.x, v2.y, v2.z, v2.w, v3.x, v3.y, v3.z, v3.w};
    float a0 = 0.f, a1 = 0.f, a2 = 0.f, a3 = 0.f;
#pragma unroll
    for (int k = 0; k < 16; k++) {
        a0 = fmaf(eav[k], w[k * 4 + 0], a0);
        a1 = fmaf(eav[k], w[k * 4 + 1], a1);
        a2 = fmaf(eav[k], w[k * 4 + 2], a2);
        a3 = fmaf(eav[k], w[k * 4 + 3], a3);
    }
    uint2 ae2; ae2.x = pk16(a0, a1); ae2.y = pk16(a2, a3);
    *(uint2*)(ae16c + (size_t)pos * 2) = ae2;
    uint4 pa, pb;
    pa.x = pk16(eav[0], eav[1]);  pa.y = pk16(eav[2], eav[3]);
    pa.z = pk16(eav[4], eav[5]);  pa.w = pk16(eav[6], eav[7]);
    pb.x = pk16(eav[8], eav[9]);  pb.y = pk16(eav[10], eav[11]);
    pb.z = pk16(eav[12], eav[13]); pb.w = pk16(eav[14], eav[15]);
    uint4* d16 = (uint4*)(ea16_csr + (size_t)pos * 8);
    d16[0] = pa; d16[1] = pb;
}

// ---------------- per-timestep kernels ----------------

// MFMA xp+aij from f32 node features (step 0 only), f16 xp.
__global__ __launch_bounds__(256) void k_xpaij(
    const float* __restrict__ xc, const f16* __restrict__ WnB,
    const f16* __restrict__ awB, f16* __restrict__ xp16,
    float* __restrict__ aijI, float* __restrict__ aijJ)
{
    int t = threadIdx.x, w = t >> 6, l = t & 63;
    int lg = l >> 4, ll = l & 15;
    int wbase = blockIdx.x * 64 + w * 16;
    int nodeA = wbase + ll;
    int nA = nodeA < NNODES ? nodeA : NNODES - 1;

    f16x8 afr[2];
#pragma unroll
    for (int ks = 0; ks < 2; ks++) {
        const float* xpr = xc + (size_t)nA * 64 + ks * 32 + lg * 8;
        float4 a0 = *(const float4*)xpr;
        float4 a1 = *(const float4*)(xpr + 4);
        f16x8 v;
        v[0] = (f16)a0.x; v[1] = (f16)a0.y; v[2] = (f16)a0.z; v[3] = (f16)a0.w;
        v[4] = (f16)a1.x; v[5] = (f16)a1.y; v[6] = (f16)a1.z; v[7] = (f16)a1.w;
        afr[ks] = v;
    }
    f32x4 zero = {0.f, 0.f, 0.f, 0.f};
    f32x4 c[16];
#pragma unroll
    for (int tt = 0; tt < 16; tt++) c[tt] = zero;
    f32x4 caw = zero;
    const f16x8* WnV = (const f16x8*)WnB;
    const f16x8* awV = (const f16x8*)awB;
#pragma unroll
    for (int ks = 0; ks < 2; ks++) {
        caw = __builtin_amdgcn_mfma_f32_16x16x32_f16(afr[ks], awV[ks * 64 + l], caw, 0, 0, 0);
#pragma unroll
        for (int tt = 0; tt < 16; tt++)
            c[tt] = __builtin_amdgcn_mfma_f32_16x16x32_f16(
                afr[ks], WnV[(ks * 16 + tt) * 64 + l], c[tt], 0, 0, 0);
    }
#pragma unroll
    for (int i = 0; i < 4; i++) {
        int node = wbase + lg * 4 + i;
        if (node < NNODES) {
            f16x8 o0, o1;
#pragma unroll
            for (int tt = 0; tt < 8; tt++) o0[tt] = (f16)c[tt][i];
#pragma unroll
            for (int tt = 0; tt < 8; tt++) o1[tt] = (f16)c[8 + tt][i];
            f16* dstp = xp16 + (size_t)node * 256 + ll * 16;
            *(f16x8*)dstp = o0;
            *(f16x8*)(dstp + 8) = o1;
            if (ll < 4)      aijI[(size_t)node * 4 + ll] = caw[i];
            else if (ll < 8) aijJ[(size_t)node * 4 + (ll - 4)] = caw[i];
        }
    }
}

#define LEAKY(v) ((v) > 0.f ? (v) : 0.2f * (v))

// Softmax + MFMA aggregation: one wave per dst node, 4 nodes/block.
// R18 form restored verbatim: forcing VGPR<=64 via __launch_bounds__(256,8)
// (R19) miscompiled/corrupted results; 72 VGPR @ 28% occupancy is the
// verified-best configuration for this decomposition.
__global__ __launch_bounds__(256) void k_node(
    const int* __restrict__ row_ptr, const int* __restrict__ csr_src,
    const uint* __restrict__ ae16c, const float* __restrict__ aijI,
    const float* __restrict__ aijJ, const f16* __restrict__ xp16,
    const uint* __restrict__ ea16_csr, const f16* __restrict__ WeB,
    f16* __restrict__ aggr16)
{
    __shared__ float wbuf[4][64][4];
    __shared__ uint  eabuf[4][64][8];
    __shared__ int   srcbuf[4][64];
    int t = threadIdx.x, wid = t >> 6, lane = t & 63;
    int ll = lane & 15, g = lane >> 4;
    int n = blockIdx.x * 4 + wid;
    uint4 z4 = {0u, 0u, 0u, 0u};
    *(uint4*)&eabuf[wid][lane][0] = z4;
    *(uint4*)&eabuf[wid][lane][4] = z4;
    f16x4 wb[16];
#pragma unroll
    for (int tt = 0; tt < 16; tt++)
        wb[tt] = *(const f16x4*)(WeB + (size_t)(tt * 64 + lane) * 4);
    int r0 = row_ptr[n], r1 = row_ptr[n + 1];
    int deg = r1 - r0;
    float acc[16];
#pragma unroll
    for (int tt = 0; tt < 16; tt++) acc[tt] = 0.f;
    f32x4 zacc = {0.f, 0.f, 0.f, 0.f};

    auto agg_chunk = [&](int c) {
        int4 s4 = *(const int4*)&srcbuf[wid][c * 16 + g * 4];
        const f16* xr0 = xp16 + ((size_t)(uint)s4.x) * 256 + ll * 16;
        const f16* xr1 = xp16 + ((size_t)(uint)s4.y) * 256 + ll * 16;
        const f16* xr2 = xp16 + ((size_t)(uint)s4.z) * 256 + ll * 16;
        const f16* xr3 = xp16 + ((size_t)(uint)s4.w) * 256 + ll * 16;
        uint4 xA[4], xB[4];
        xA[0] = *(const uint4*)xr0; xB[0] = *(const uint4*)(xr0 + 8);
        xA[1] = *(const uint4*)xr1; xB[1] = *(const uint4*)(xr1 + 8);
        xA[2] = *(const uint4*)xr2; xB[2] = *(const uint4*)(xr2 + 8);
        xA[3] = *(const uint4*)xr3; xB[3] = *(const uint4*)(xr3 + 8);
        f16x4 eaf = *(const f16x4*)((const f16*)&eabuf[wid][c * 16 + ll][0] + g * 4);
        float4 w4 = *(const float4*)&wbuf[wid][c * 16 + ll][0];
        f16 av[4] = {(f16)w4.x, (f16)w4.y, (f16)w4.z, (f16)w4.w};
        f16x4 Ah[4];
#pragma unroll
        for (int h = 0; h < 4; h++)
#pragma unroll
            for (int j = 0; j < 4; j++)
                Ah[h][j] = eaf[j] * av[h];
#pragma unroll
        for (int h = 0; h < 4; h++) {
            f32x4 p0 = __builtin_amdgcn_mfma_f32_16x16x16f16(Ah[h], wb[h * 4 + 0], zacc, 0, 0, 0);
            f32x4 p1 = __builtin_amdgcn_mfma_f32_16x16x16f16(Ah[h], wb[h * 4 + 1], zacc, 0, 0, 0);
            f32x4 p2 = __builtin_amdgcn_mfma_f32_16x16x16f16(Ah[h], wb[h * 4 + 2], zacc, 0, 0, 0);
            f32x4 p3 = __builtin_amdgcn_mfma_f32_16x16x16f16(Ah[h], wb[h * 4 + 3], zacc, 0, 0, 0);
#pragma unroll
            for (int ttl = 0; ttl < 4; ttl++) {
                int tt = h * 4 + ttl;
                f32x4 pv = ttl == 0 ? p0 : (ttl == 1 ? p1 : (ttl == 2 ? p2 : p3));
                int q = tt & 7;
#pragma unroll
                for (int r = 0; r < 4; r++) {
                    uint4 xs = (tt < 8) ? xA[r] : xB[r];
                    uint wrd = (q >> 1) == 0 ? xs.x
                             : ((q >> 1) == 1 ? xs.y : ((q >> 1) == 2 ? xs.z : xs.w));
                    float pvf = pv[r];
                    if (q & 1) FMAMIX_HI(acc[tt], pvf, wrd);
                    else       FMAMIX_LO(acc[tt], pvf, wrd);
                }
            }
        }
    };

    if (deg > 0 && deg <= 64) {
        float4 ai = *(const float4*)(aijI + (size_t)n * 4);
        float al0 = -1e30f, al1 = -1e30f, al2 = -1e30f, al3 = -1e30f;
        int sreg = 0;
        if (lane < deg) {
            int p = r0 + lane;
            sreg = csr_src[p];
            uint2 ae2 = *(const uint2*)(ae16c + (size_t)p * 2);
            f16x2 aelo = bc16(ae2.x), aehi = bc16(ae2.y);
            float4 aj = *(const float4*)(aijJ + (size_t)sreg * 4);
            const uint4* ep16 = (const uint4*)(ea16_csr + (size_t)p * 8);
            uint4 ua = ep16[0], ub = ep16[1];
            *(uint4*)&eabuf[wid][lane][0] = ua;
            *(uint4*)&eabuf[wid][lane][4] = ub;
            al0 = LEAKY(ai.x + (float)aelo[0] + aj.x);
            al1 = LEAKY(ai.y + (float)aelo[1] + aj.y);
            al2 = LEAKY(ai.z + (float)aehi[0] + aj.z);
            al3 = LEAKY(ai.w + (float)aehi[1] + aj.w);
        }
        srcbuf[wid][lane] = (lane < deg) ? sreg : 0;
        float m0, m1, m2, m3, s0, s1, s2, s3;
        float p0, p1, p2, p3;
        if (deg <= 16) {
            m0 = wred_max16(al0); m1 = wred_max16(al1);
            m2 = wred_max16(al2); m3 = wred_max16(al3);
            p0 = (lane < deg) ? __expf(al0 - m0) : 0.f;
            p1 = (lane < deg) ? __expf(al1 - m1) : 0.f;
            p2 = (lane < deg) ? __expf(al2 - m2) : 0.f;
            p3 = (lane < deg) ? __expf(al3 - m3) : 0.f;
            s0 = wred_sum16(p0); s1 = wred_sum16(p1);
            s2 = wred_sum16(p2); s3 = wred_sum16(p3);
        } else {
            m0 = wred_max(al0); m1 = wred_max(al1);
            m2 = wred_max(al2); m3 = wred_max(al3);
            p0 = (lane < deg) ? __expf(al0 - m0) : 0.f;
            p1 = (lane < deg) ? __expf(al1 - m1) : 0.f;
            p2 = (lane < deg) ? __expf(al2 - m2) : 0.f;
            p3 = (lane < deg) ? __expf(al3 - m3) : 0.f;
            s0 = wred_sum(p0); s1 = wred_sum(p1);
            s2 = wred_sum(p2); s3 = wred_sum(p3);
        }
        float4 w4v;
        w4v.x = p0 * (1.f / (s0 + 1e-16f));
        w4v.y = p1 * (1.f / (s1 + 1e-16f));
        w4v.z = p2 * (1.f / (s2 + 1e-16f));
        w4v.w = p3 * (1.f / (s3 + 1e-16f));
        *(float4*)&wbuf[wid][lane][0] = w4v;
        asm volatile("s_waitcnt lgkmcnt(0)" ::: "memory");
        int nch = (deg + 15) >> 4;
        for (int c = 0; c < nch; c++) agg_chunk(c);
    } else if (deg > 0) {
        float4 ai = *(const float4*)(aijI + (size_t)n * 4);
        float m0 = -1e30f, m1 = -1e30f, m2 = -1e30f, m3 = -1e30f;
        float s0 = 0.f, s1 = 0.f, s2 = 0.f, s3 = 0.f;
        for (int base = r0; base < r1; base += 64) {
            int p = base + lane;
            if (p < r1) {
                int s = csr_src[p];
                uint2 ae2 = *(const uint2*)(ae16c + (size_t)p * 2);
                f16x2 aelo = bc16(ae2.x), aehi = bc16(ae2.y);
                float4 aj = *(const float4*)(aijJ + (size_t)s * 4);
                float al0 = LEAKY(ai.x + (float)aelo[0] + aj.x);
                float al1 = LEAKY(ai.y + (float)aelo[1] + aj.y);
                float al2 = LEAKY(ai.z + (float)aehi[0] + aj.z);
                float al3 = LEAKY(ai.w + (float)aehi[1] + aj.w);
                float nm;
                nm = fmaxf(m0, al0); s0 = s0 * __expf(m0 - nm) + __expf(al0 - nm); m0 = nm;
                nm = fmaxf(m1, al1); s1 = s1 * __expf(m1 - nm) + __expf(al1 - nm); m1 = nm;
                nm = fmaxf(m2, al2); s2 = s2 * __expf(m2 - nm) + __expf(al2 - nm); m2 = nm;
                nm = fmaxf(m3, al3); s3 = s3 * __expf(m3 - nm) + __expf(al3 - nm); m3 = nm;
            }
        }
#pragma unroll
        for (int off = 32; off; off >>= 1) {
            float om, os, nm;
            om = __shfl_xor(m0, off, 64); os = __shfl_xor(s0, off, 64);
            nm = fmaxf(m0, om); s0 = s0 * __expf(m0 - nm) + os * __expf(om - nm); m0 = nm;
            om = __shfl_xor(m1, off, 64); os = __shfl_xor(s1, off, 64);
            nm = fmaxf(m1, om); s1 = s1 * __expf(m1 - nm) + os * __expf(om - nm); m1 = nm;
            om = __shfl_xor(m2, off, 64); os = __shfl_xor(s2, off, 64);
            nm = fmaxf(m2, om); s2 = s2 * __expf(m2 - nm) + os * __expf(om - nm); m2 = nm;
            om = __shfl_xor(m3, off, 64); os = __shfl_xor(s3, off, 64);
            nm = fmaxf(m3, om); s3 = s3 * __expf(m3 - nm) + os * __expf(om - nm); m3 = nm;
        }
        float rd0 = 1.f / (s0 + 1e-16f), rd1 = 1.f / (s1 + 1e-16f);
        float rd2 = 1.f / (s2 + 1e-16f), rd3 = 1.f / (s3 + 1e-16f);
        for (int base = r0; base < r1; base += 64) {
            int cnt = min(64, r1 - base);
            float4 w4v = {0.f, 0.f, 0.f, 0.f};
            int sreg = 0;
            if (lane < cnt) {
                int p = base + lane;
                sreg = csr_src[p];
                uint2 ae2 = *(const uint2*)(ae16c + (size_t)p * 2);
                f16x2 aelo = bc16(ae2.x), aehi = bc16(ae2.y);
                float4 aj = *(const float4*)(aijJ + (size_t)sreg * 4);
                const uint4* ep16 = (const uint4*)(ea16_csr + (size_t)p * 8);
                uint4 ua = ep16[0], ub = ep16[1];
                *(uint4*)&eabuf[wid][lane][0] = ua;
                *(uint4*)&eabuf[wid][lane][4] = ub;
                float al0 = LEAKY(ai.x + (float)aelo[0] + aj.x);
                float al1 = LEAKY(ai.y + (float)aelo[1] + aj.y);
                float al2 = LEAKY(ai.z + (float)aehi[0] + aj.z);
                float al3 = LEAKY(ai.w + (float)aehi[1] + aj.w);
                w4v.x = __expf(al0 - m0) * rd0;
                w4v.y = __expf(al1 - m1) * rd1;
                w4v.z = __expf(al2 - m2) * rd2;
                w4v.w = __expf(al3 - m3) * rd3;
            } else {
                *(uint4*)&eabuf[wid][lane][0] = z4;
                *(uint4*)&eabuf[wid][lane][4] = z4;
            }
            *(float4*)&wbuf[wid][lane][0] = w4v;
            srcbuf[wid][lane] = (lane < cnt) ? sreg : 0;
            asm volatile("s_waitcnt lgkmcnt(0)" ::: "memory");
            int nch = (cnt + 15) >> 4;
            for (int c = 0; c < nch; c++) agg_chunk(c);
            asm volatile("s_waitcnt lgkmcnt(0)" ::: "memory");
        }
    }
#pragma unroll
    for (int tt = 0; tt < 16; tt++) {
        float v = acc[tt];
        v += __shfl_xor(v, 16, 64);
        v += __shfl_xor(v, 32, 64);
        acc[tt] = v;
    }
    f16* ag = aggr16 + (size_t)n * 256;
#pragma unroll
    for (int tt = 0; tt < 16; tt++)
        if ((tt >> 2) == g) ag[tt * 16 + ll] = (f16)acc[tt];
}

// MFMA k_post: celu(aggr16@WsP+b) -> GRU -> LayerNorm, fused next-step xp/aij.
// last=1: write final xc to out, skip xp/aij and the dead h_out store.
__global__ __launch_bounds__(256) void k_post(
    const f16* __restrict__ aggr16, const f16* __restrict__ WsP,
    const float* __restrict__ bvec, const float* __restrict__ h_in,
    float* __restrict__ h_out, const f16* __restrict__ WihP,
    const f16* __restrict__ WhhP, const float* __restrict__ bih,
    const float* __restrict__ bhh, const float* __restrict__ gamma,
    const float* __restrict__ beta, const f16* __restrict__ WnB,
    const f16* __restrict__ awB, f16* __restrict__ xp16,
    float* __restrict__ aijI, float* __restrict__ aijJ,
    float* __restrict__ xc_out, int last)
{
    __shared__ __align__(16) f16 m_lds[4][16][72];  // 18 KB, +8 pad
    int t = threadIdx.x, w = t >> 6, l = t & 63;
    int lg = l >> 4, ll = l & 15;
    int nb = blockIdx.x * 64 + w * 16;
    int nodeA = nb + ll;
    int nodeAc = nodeA < NNODES ? nodeA : NNODES - 1;

    f32x4 zero = {0.f, 0.f, 0.f, 0.f};
    f32x4 acc1[4];
#pragma unroll
    for (int tt = 0; tt < 4; tt++) acc1[tt] = zero;
    const f16x8* WsV = (const f16x8*)WsP;
#pragma unroll
    for (int ks = 0; ks < 8; ks++) {
        f16x8 a = *(const f16x8*)(aggr16 + (size_t)nodeAc * 256 + ks * 32 + lg * 8);
#pragma unroll
        for (int tt = 0; tt < 4; tt++) {
            f16x8 b = WsV[(ks * 4 + tt) * 64 + l];
            acc1[tt] = __builtin_amdgcn_mfma_f32_16x16x32_f16(a, b, acc1[tt], 0, 0, 0);
        }
    }
#pragma unroll
    for (int tt = 0; tt < 4; tt++) {
        float bj = bvec[tt * 16 + ll];
#pragma unroll
        for (int i = 0; i < 4; i++) {
            float v = acc1[tt][i] + bj;
            v = v > 0.f ? v : (__expf(v) - 1.f);  // celu
            m_lds[w][lg * 4 + i][tt * 16 + ll] = (f16)v;
        }
    }
    asm volatile("s_waitcnt lgkmcnt(0)" ::: "memory");

    f16x8 mf[2], hf[2];
#pragma unroll
    for (int ks = 0; ks < 2; ks++) {
        mf[ks] = *(const f16x8*)(&m_lds[w][ll][ks * 32 + lg * 8]);
        const float* hp = h_in + (size_t)nodeAc * 64 + ks * 32 + lg * 8;
        float4 h0 = *(const float4*)(hp);
        float4 h1 = *(const float4*)(hp + 4);
        f16x8 hh;
        hh[0] = (f16)h0.x; hh[1] = (f16)h0.y; hh[2] = (f16)h0.z; hh[3] = (f16)h0.w;
        hh[4] = (f16)h1.x; hh[5] = (f16)h1.y; hh[6] = (f16)h1.z; hh[7] = (f16)h1.w;
        hf[ks] = hh;
    }
    f32x4 accI[12], accH[12];
#pragma unroll
    for (int tt = 0; tt < 12; tt++) { accI[tt] = zero; accH[tt] = zero; }
    const f16x8* WiV = (const f16x8*)WihP;
    const f16x8* WhV = (const f16x8*)WhhP;
#pragma unroll
    for (int ks = 0; ks < 2; ks++) {
#pragma unroll
        for (int tt = 0; tt < 12; tt++) {
            f16x8 bi = WiV[(ks * 12 + tt) * 64 + l];
            accI[tt] = __builtin_amdgcn_mfma_f32_16x16x32_f16(mf[ks], bi, accI[tt], 0, 0, 0);
            f16x8 bh = WhV[(ks * 12 + tt) * 64 + l];
            accH[tt] = __builtin_amdgcn_mfma_f32_16x16x32_f16(hf[ks], bh, accH[tt], 0, 0, 0);
        }
    }

    float bI[12], bH[12];
#pragma unroll
    for (int tt = 0; tt < 12; tt++) {
        bI[tt] = bih[ll + 16 * tt];
        bH[tt] = bhh[ll + 16 * tt];
    }
    float ga[4], be[4];
#pragma unroll
    for (int u = 0; u < 4; u++) { ga[u] = gamma[ll + 16 * u]; be[u] = beta[ll + 16 * u]; }
    float hnew[4][4];
#pragma unroll
    for (int i = 0; i < 4; i++) {
        int node = nb + lg * 4 + i;
        int nc = node < NNODES ? node : NNODES - 1;
        const float* hrow = h_in + (size_t)nc * 64 + ll;
#pragma unroll
        for (int u = 0; u < 4; u++) {
            float hv = hrow[16 * u];
            float r = 1.f / (1.f + __expf(-(accI[u][i] + bI[u] + accH[u][i] + bH[u])));
            float z = 1.f / (1.f + __expf(-(accI[u + 4][i] + bI[u + 4] + accH[u + 4][i] + bH[u + 4])));
            float pre = accI[u + 8][i] + bI[u + 8] + r * (accH[u + 8][i] + bH[u + 8]);
            float e2 = __expf(2.f * pre);
            float nn = 1.f - 2.f / (e2 + 1.f);  // tanh, inf-safe
            hnew[i][u] = (1.f - z) * nn + z * hv;
        }
    }
#pragma unroll
    for (int i = 0; i < 4; i++) {
        float s = hnew[i][0] + hnew[i][1] + hnew[i][2] + hnew[i][3];
        float q = hnew[i][0] * hnew[i][0] + hnew[i][1] * hnew[i][1]
                + hnew[i][2] * hnew[i][2] + hnew[i][3] * hnew[i][3];
#pragma unroll
        for (int off = 1; off < 16; off <<= 1) {
            s += __shfl_xor(s, off, 64);
            q += __shfl_xor(q, off, 64);
        }
        float mu = s * (1.f / 64.f);
        float var = q * (1.f / 64.f) - mu * mu;
        float rstd = rsqrtf(var + 1e-5f);
        int node = nb + lg * 4 + i;
        bool ok = node < NNODES;
        float* ho = h_out + (size_t)node * 64 + ll;
        float* xo = xc_out + (size_t)node * 64 + ll;
#pragma unroll
        for (int u = 0; u < 4; u++) {
            float xcv = (hnew[i][u] - mu) * rstd * ga[u] + be[u];
            if (ok) {
                if (last) xo[16 * u] = xcv;
                else      ho[16 * u] = hnew[i][u];
            }
            m_lds[w][lg * 4 + i][16 * u + ll] = (f16)xcv;
        }
    }
    if (last) return;
    asm volatile("s_waitcnt lgkmcnt(0)" ::: "memory");

    // ---- fused next-step xp/aij ----
    f16x8 afr[2];
#pragma unroll
    for (int ks = 0; ks < 2; ks++)
        afr[ks] = *(const f16x8*)(&m_lds[w][ll][ks * 32 + lg * 8]);
    f32x4 c[16];
#pragma unroll
    for (int tt = 0; tt < 16; tt++) c[tt] = zero;
    f32x4 caw = zero;
    const f16x8* WnV = (const f16x8*)WnB;
    const f16x8* awV = (const f16x8*)awB;
#pragma unroll
    for (int ks = 0; ks < 2; ks++) {
        caw = __builtin_amdgcn_mfma_f32_16x16x32_f16(afr[ks], awV[ks * 64 + l], caw, 0, 0, 0);
#pragma unroll
        for (int tt = 0; tt < 16; tt++)
            c[tt] = __builtin_amdgcn_mfma_f32_16x16x32_f16(
                afr[ks], WnV[(ks * 16 + tt) * 64 + l], c[tt], 0, 0, 0);
    }
#pragma unroll
    for (int i = 0; i < 4; i++) {
        int node = nb + lg * 4 + i;
        if (node < NNODES) {
            f16x8 o0, o1;
#pragma unroll
            for (int tt = 0; tt < 8; tt++) o0[tt] = (f16)c[tt][i];
#pragma unroll
            for (int tt = 0; tt < 8; tt++) o1[tt] = (f16)c[8 + tt][i];
            f16* dstp = xp16 + (size_t)node * 256 + ll * 16;
            *(f16x8*)dstp = o0;
            *(f16x8*)(dstp + 8) = o1;
            if (ll < 4)      aijI[(size_t)node * 4 + ll] = caw[i];
            else if (ll < 8) aijJ[(size_t)node * 4 + (ll - 4)] = caw[i];
        }
    }
}

// ---------------- launcher ----------------

extern "C" void kernel_launch(void* const* d_in, const int* in_sizes, int n_in,
                              void* d_out, int out_size, void* d_ws, size_t ws_size,
                              hipStream_t stream)
{
    const float* x         = (const float*)d_in[0];
    const int*   edge_index= (const int*)d_in[1];
    const float* edge_attr = (const float*)d_in[2];
    const float* Wn        = (const float*)d_in[3];
    const float* We        = (const float*)d_in[4];
    const float* Wa        = (const float*)d_in[5];
    const float* Ws        = (const float*)d_in[6];
    const float* bv        = (const float*)d_in[7];
    const float* Wih       = (const float*)d_in[8];
    const float* Whh       = (const float*)d_in[9];
    const float* bih       = (const float*)d_in[10];
    const float* bhh       = (const float*)d_in[11];
    const float* gamma     = (const float*)d_in[12];
    const float* beta      = (const float*)d_in[13];
    float* out = (float*)d_out;

    const int* src = edge_index;
    const int* dst = edge_index + NEDGES;

    char* w = (char*)d_ws;
    auto alloc = [&](size_t bytes) {
        char* p = w;
        w += (bytes + 255) & ~(size_t)255;
        return p;
    };
    f16*   xp16     = (f16*)alloc((size_t)NNODES * 256 * 2);
    f16*   aggr16   = (f16*)alloc((size_t)NNODES * 256 * 2);
    uint*  ae16c    = (uint*)alloc((size_t)NEDGES * 2 * 4);
    uint*  ea16_csr = (uint*)alloc((size_t)NEDGES * 8 * 4);
    float* hbuf     = (float*)alloc((size_t)NNODES * 64 * 4);
    float* aijI     = (float*)alloc((size_t)NNODES * 4 * 4);
    float* aijJ     = (float*)alloc((size_t)NNODES * 4 * 4);
    int*   counts   = (int*)alloc((size_t)NNODES * 4);
    int*   rankv    = (int*)alloc((size_t)NEDGES * 4);
    int*   row_ptr  = (int*)alloc((size_t)(NNODES + 1) * 4);
    int*   csr_src  = (int*)alloc((size_t)NEDGES * 4);
    int*   psum     = (int*)alloc(64 * 4);
    float* wnwa0    = (float*)alloc(256 * 4);
    float* wnwa2    = (float*)alloc(256 * 4);
    float* wewa1    = (float*)alloc(64 * 4);
    f16*   WeB      = (f16*)alloc(1024 * 4 * 2);
    f16*   WsP      = (f16*)alloc(2048 * 8 * 2);
    f16*   WihP     = (f16*)alloc(1536 * 8 * 2);
    f16*   WhhP     = (f16*)alloc(1536 * 8 * 2);
    f16*   WnB      = (f16*)alloc(2048 * 8 * 2);
    f16*   awB      = (f16*)alloc(128 * 8 * 2);

    const int NSCAN = (NNODES + 1023) / 1024;   // 49

    k_fold1<<<1, 256, 0, stream>>>(Wn, We, Wa, wnwa0, wnwa2, wewa1);
    hipMemsetAsync(counts, 0, (size_t)NNODES * 4, stream);
    k_hist<<<NEDGES / 256, 256, 0, stream>>>(dst, counts, rankv);
    k_fold2<<<8, 256, 0, stream>>>(Wn, We, Wih, Whh, Ws, wnwa0, wnwa2,
                                   WeB, WsP, WihP, WhhP, WnB, awB);
    k_scan1<<<NSCAN, 1024, 0, stream>>>(counts, psum);
    k_scan0<<<1, 64, 0, stream>>>(psum, NSCAN);
    k_scan2<<<NSCAN, 1024, 0, stream>>>(counts, psum, row_ptr);
    k_scatter<<<NEDGES / 256, 256, 0, stream>>>(src, dst, rankv, edge_attr,
                                                wewa1, row_ptr, csr_src,
                                                ae16c, ea16_csr);

    k_xpaij<<<(NNODES + 63) / 64, 256, 0, stream>>>(x, WnB, awB,
                                                    xp16, aijI, aijJ);
    for (int step = 0; step < 3; step++) {
        const float* h_in = (step == 0) ? x : hbuf;
        k_node<<<NNODES / 4, 256, 0, stream>>>(row_ptr, csr_src, ae16c, aijI,
                                               aijJ, xp16, ea16_csr, WeB, aggr16);
        k_post<<<(NNODES + 63) / 64, 256, 0, stream>>>(
            aggr16, WsP, bv, h_in, hbuf, WihP, WhhP, bih, bhh, gamma, beta,
            WnB, awB, xp16, aijI, aijJ, out, step == 2 ? 1 : 0);
    }
}